// Round 7
// baseline (904.249 us; speedup 1.0000x reference)
//
#include <hip/hip_runtime.h>
#include <hip/hip_bf16.h>
#include <math.h>

// ---------------------------------------------------------------------------
// Model constants
// ---------------------------------------------------------------------------
#define NBATCH 5
#define SEQ    1024
#define T      1025          // SEQ + 1 (cls token)
#define ROWS   (NBATCH * T)  // 5125
#define MP     5248          // ROWS padded to 41*128 for MFMA tiles
#define DM     512
#define DFF    2048
#define NHEAD  8
#define HD     64
#define NTOK   51
#define MLPDIM 256
#define NCLS   7
#define GH     3
#define GHID   64
#define GCLS   5
#define NGRAPH (SEQ * 5)     // 5120
#define QKVN   1536          // fused QKV output width
#define TPAD   1152          // V^T row stride (only t<1025 ever read)

typedef __attribute__((ext_vector_type(8))) short bf16x8;
typedef __attribute__((ext_vector_type(4))) float f32x4;

#define GM_AS(p)  ((const __attribute__((address_space(1))) void*)(p))
#define LDS_AS(p) ((__attribute__((address_space(3))) void*)(p))

__device__ __forceinline__ unsigned short f2bf(float f) {
    unsigned int u = __float_as_uint(f);
    unsigned int r = (u + 0x7FFFu + ((u >> 16) & 1u)) >> 16;
    return (unsigned short)r;
}
__device__ __forceinline__ float bf2f(unsigned short u) {
    return __uint_as_float((unsigned int)u << 16);
}

// ---------------------------------------------------------------------------
// Mega-setup: all weight transposes (fp32->bf16, [K][N]->[N][K]) + bias concat.
// ---------------------------------------------------------------------------
__global__ __launch_bounds__(256) void setup_kernel(
    const float* __restrict__ Wq, const float* __restrict__ Wk,
    const float* __restrict__ Wv, const float* __restrict__ Wo_,
    const float* __restrict__ W1, const float* __restrict__ W2,
    const float* __restrict__ bq, const float* __restrict__ bk,
    const float* __restrict__ bv,
    unsigned short* __restrict__ Wqkvt, unsigned short* __restrict__ Wot,
    unsigned short* __restrict__ W1t, unsigned short* __restrict__ W2t,
    float* __restrict__ bqkv)
{
    int id = blockIdx.x;
    if (id >= 12288) {              // bias concat: 4 blocks, one per layer
        int i = id - 12288;
        #pragma unroll
        for (int rep = 0; rep < 2; ++rep) {
            int t = threadIdx.x + rep * 256;
            bqkv[i * QKVN + t]        = bq[i * DM + t];
            bqkv[i * QKVN + 512 + t]  = bk[i * DM + t];
            bqkv[i * QKVN + 1024 + t] = bv[i * DM + t];
        }
        return;
    }
    const float* W; unsigned short* Wt; int K, N, z, bx, by; long dstride;
    if (id < 4096) {                // Wq/Wk/Wv/Wo: 512x512
        int g = id >> 10, lid = id & 1023;
        K = DM; N = DM;
        z = lid >> 8; int r2 = lid & 255; by = r2 >> 4; bx = r2 & 15;
        if (g < 3) { W = (g == 0) ? Wq : (g == 1) ? Wk : Wv;
                     Wt = Wqkvt + (size_t)g * DM * DM; dstride = (long)QKVN * DM; }
        else       { W = Wo_; Wt = Wot; dstride = (long)DM * DM; }
    } else if (id < 8192) {         // W1: K=512, N=2048
        int lid = id - 4096;
        K = DM; N = DFF;
        z = lid >> 10; int r2 = lid & 1023; by = r2 >> 6; bx = r2 & 63;
        W = W1; Wt = W1t; dstride = (long)DM * DFF;
    } else {                        // W2: K=2048, N=512
        int lid = id - 8192;
        K = DFF; N = DM;
        z = lid >> 10; int r2 = lid & 1023; by = r2 >> 4; bx = r2 & 15;
        W = W2; Wt = W2t; dstride = (long)DFF * DM;
    }
    const float* Wm = W + (size_t)z * K * N;
    unsigned short* Wo2 = Wt + (size_t)z * dstride;
    __shared__ float tile[32][33];
    int bX = bx * 32, bY = by * 32;
    int tx = threadIdx.x & 31, ty = threadIdx.x >> 5;
    #pragma unroll
    for (int i = 0; i < 32; i += 8)
        tile[ty + i][tx] = Wm[(size_t)(bY + ty + i) * N + bX + tx];
    __syncthreads();
    #pragma unroll
    for (int i = 0; i < 32; i += 8)
        Wo2[(size_t)(bX + ty + i) * K + bY + tx] = f2bf(tile[tx][ty + i]);
}

// ---------------------------------------------------------------------------
// bf16 MFMA GEMM: C[M][N] = A[M][K] @ Bt[N][K]^T + bias. 128x128 tile, BK=64.
// ---------------------------------------------------------------------------
__global__ __launch_bounds__(256) void gemm_mfma(
    const unsigned short* __restrict__ A, const unsigned short* __restrict__ Bt,
    const float* __restrict__ bias, float* __restrict__ Cf,
    unsigned short* __restrict__ Cb, int N, int K, int relu)
{
    __shared__ unsigned short As[128 * 64];
    __shared__ unsigned short Bs[128 * 64];
    int tid = threadIdx.x;
    int l = tid & 63, w = tid >> 6;
    int wr = w & 1, wc = w >> 1;
    int mlane = l & 15, quad = l >> 4;
    int m0 = blockIdx.y * 128, n0 = blockIdx.x * 128;

    f32x4 acc[4][4] = {};

    for (int k0 = 0; k0 < K; k0 += 64) {
        __syncthreads();
        #pragma unroll
        for (int it = 0; it < 4; ++it) {
            int c = tid + it * 256;
            int row = c >> 3, cc = c & 7;
            const unsigned short* ga = A  + (size_t)(m0 + row) * K + k0 + cc * 8;
            __builtin_amdgcn_global_load_lds(GM_AS(ga), LDS_AS(As + c * 8), 16, 0, 0);
            const unsigned short* gb = Bt + (size_t)(n0 + row) * K + k0 + cc * 8;
            __builtin_amdgcn_global_load_lds(GM_AS(gb), LDS_AS(Bs + c * 8), 16, 0, 0);
        }
        __syncthreads();
        #pragma unroll
        for (int half = 0; half < 2; ++half) {
            int ko = half * 32 + quad * 8;
            bf16x8 afrag[4], bfrag[4];
            #pragma unroll
            for (int mi = 0; mi < 4; ++mi)
                afrag[mi] = *(const bf16x8*)(As + (wr * 64 + mi * 16 + mlane) * 64 + ko);
            #pragma unroll
            for (int ni = 0; ni < 4; ++ni)
                bfrag[ni] = *(const bf16x8*)(Bs + (wc * 64 + ni * 16 + mlane) * 64 + ko);
            #pragma unroll
            for (int mi = 0; mi < 4; ++mi)
                #pragma unroll
                for (int ni = 0; ni < 4; ++ni)
                    acc[mi][ni] = __builtin_amdgcn_mfma_f32_16x16x32_bf16(
                        afrag[mi], bfrag[ni], acc[mi][ni], 0, 0, 0);
        }
    }

    #pragma unroll
    for (int mi = 0; mi < 4; ++mi) {
        #pragma unroll
        for (int r = 0; r < 4; ++r) {
            int gm = m0 + wr * 64 + mi * 16 + quad * 4 + r;
            size_t rowoff = (size_t)gm * N;
            #pragma unroll
            for (int ni = 0; ni < 4; ++ni) {
                int gn = n0 + wc * 64 + ni * 16 + mlane;
                float val = acc[mi][ni][r] + bias[gn];
                if (relu) val = fmaxf(val, 0.f);
                if (Cb) Cb[rowoff + gn] = f2bf(val);
                else    Cf[rowoff + gn] = val;
            }
        }
    }
}

// ---------------------------------------------------------------------------
// Split-K bf16 MFMA GEMM: fp32 atomicAdd of partials directly into h
// (which already holds the residual). Removes the bf16 partial round trip
// (~64 MB/layer write+read) and the add_lnp np-loop. Padding rows skipped.
// ---------------------------------------------------------------------------
__global__ __launch_bounds__(256) void gemm_mfma_sk(
    const unsigned short* __restrict__ A, const unsigned short* __restrict__ Bt,
    float* __restrict__ hacc, int N, int K)
{
    __shared__ unsigned short As[128 * 64];
    __shared__ unsigned short Bs[128 * 64];
    int tid = threadIdx.x;
    int l = tid & 63, w = tid >> 6;
    int wr = w & 1, wc = w >> 1;
    int mlane = l & 15, quad = l >> 4;
    int m0 = blockIdx.y * 128, n0 = blockIdx.x * 128;
    int kper = K / gridDim.z;
    int kbeg = blockIdx.z * kper;

    f32x4 acc[4][4] = {};

    for (int k0 = kbeg; k0 < kbeg + kper; k0 += 64) {
        __syncthreads();
        #pragma unroll
        for (int it = 0; it < 4; ++it) {
            int c = tid + it * 256;
            int row = c >> 3, cc = c & 7;
            const unsigned short* ga = A  + (size_t)(m0 + row) * K + k0 + cc * 8;
            __builtin_amdgcn_global_load_lds(GM_AS(ga), LDS_AS(As + c * 8), 16, 0, 0);
            const unsigned short* gb = Bt + (size_t)(n0 + row) * K + k0 + cc * 8;
            __builtin_amdgcn_global_load_lds(GM_AS(gb), LDS_AS(Bs + c * 8), 16, 0, 0);
        }
        __syncthreads();
        #pragma unroll
        for (int half = 0; half < 2; ++half) {
            int ko = half * 32 + quad * 8;
            bf16x8 afrag[4], bfrag[4];
            #pragma unroll
            for (int mi = 0; mi < 4; ++mi)
                afrag[mi] = *(const bf16x8*)(As + (wr * 64 + mi * 16 + mlane) * 64 + ko);
            #pragma unroll
            for (int ni = 0; ni < 4; ++ni)
                bfrag[ni] = *(const bf16x8*)(Bs + (wc * 64 + ni * 16 + mlane) * 64 + ko);
            #pragma unroll
            for (int mi = 0; mi < 4; ++mi)
                #pragma unroll
                for (int ni = 0; ni < 4; ++ni)
                    acc[mi][ni] = __builtin_amdgcn_mfma_f32_16x16x32_bf16(
                        afrag[mi], bfrag[ni], acc[mi][ni], 0, 0, 0);
        }
    }

    #pragma unroll
    for (int mi = 0; mi < 4; ++mi) {
        #pragma unroll
        for (int r = 0; r < 4; ++r) {
            int gm = m0 + wr * 64 + mi * 16 + quad * 4 + r;
            if (gm >= ROWS) continue;        // never pollute padding rows
            size_t rowoff = (size_t)gm * N;
            #pragma unroll
            for (int ni = 0; ni < 4; ++ni) {
                int gn = n0 + wc * 64 + ni * 16 + mlane;
                atomicAdd(&hacc[rowoff + gn], acc[mi][ni][r]);
            }
        }
    }
}

// ---------------------------------------------------------------------------
// V transpose per layer: vb rows (b,t) stride qs -> vt[(bh*64+d)][TPAD].
// x-grid = 17 tiles (covers t < 1088; only t < 1025 is ever read).
// ---------------------------------------------------------------------------
__global__ __launch_bounds__(256) void vtrans_kernel(
    const unsigned short* __restrict__ vb, unsigned short* __restrict__ vt, int qs)
{
    __shared__ unsigned short tile[64][72];
    int bh = blockIdx.y;
    int b = bh >> 3, h = bh & 7;
    int t0 = blockIdx.x * 64;
    int tid = threadIdx.x;
    #pragma unroll
    for (int it = 0; it < 2; ++it) {
        int c = tid + it * 256;
        int key = c >> 3, cc = c & 7;
        int gk = t0 + key; if (gk >= T) gk = T - 1;
        *(bf16x8*)(&tile[key][cc * 8]) =
            *(const bf16x8*)(vb + ((size_t)b * T + gk) * qs + h * HD + cc * 8);
    }
    __syncthreads();
    #pragma unroll
    for (int it = 0; it < 2; ++it) {
        int c = tid + it * 256;
        int d = c >> 3, cc = c & 7;
        unsigned short tmp[8];
        #pragma unroll
        for (int j = 0; j < 8; ++j) tmp[j] = tile[cc * 8 + j][d];
        *(bf16x8*)(vt + ((size_t)bh * 64 + d) * TPAD + t0 + cc * 8) = *(bf16x8*)tmp;
    }
}

// ---------------------------------------------------------------------------
// bf16 MFMA flash attention. NR=8 rounds of 128 keys cover t in [0,1024);
// the single remaining key t=1024 is a scalar rank-1 tail.
// Block = 64 queries x (b,h); 4 waves x 16 q — measured local optimum
// (2-wave: 52us occupancy-bound; 8-wave/128q: +12us; setprio: +9us).
// ---------------------------------------------------------------------------
#define AQT 64
#define NR 8    // rounds of 128 keys over [0,1024)
__global__ __launch_bounds__(256) void attn_mfma(
    const unsigned short* __restrict__ qb, const unsigned short* __restrict__ kb,
    const unsigned short* __restrict__ vt, unsigned short* __restrict__ ob,
    int qs)
{
    __shared__ unsigned short Ks[128 * 72];    // [key][72]
    __shared__ unsigned short Vs[64 * 136];    // [d][136] keys contiguous
    __shared__ unsigned short Ps[4][16 * 72];
    int bh = blockIdx.y;
    int b = bh >> 3, h = bh & 7;
    int t0 = blockIdx.x * AQT;
    int tid = threadIdx.x;
    int l = tid & 63, w = tid >> 6;
    int ml = l & 15, quad = l >> 4;
    size_t rowbase = (size_t)b * T;
    const unsigned short* vtb = vt + (size_t)bh * 64 * TPAD;

    int qrow = t0 + w * 16 + ml; if (qrow >= T) qrow = T - 1;
    const unsigned short* qp = qb + (rowbase + qrow) * qs + h * HD + quad * 8;
    bf16x8 qf0 = *(const bf16x8*)qp;
    bf16x8 qf1 = *(const bf16x8*)(qp + 32);

    int krow = tid >> 3, kcc = tid & 7;
    int vd   = tid >> 4, vck = tid & 15;

    f32x4 oacc[4] = {};
    float lrow[4] = {0.f, 0.f, 0.f, 0.f};

    bf16x8 kr[4], vr[4];
    #pragma unroll
    for (int i = 0; i < 4; ++i) {
        int gk = krow + i * 32;
        kr[i] = *(const bf16x8*)(kb + (rowbase + gk) * qs + h * HD + kcc * 8);
        vr[i] = *(const bf16x8*)(vtb + (size_t)(vd + i * 16) * TPAD + vck * 8);
    }

    for (int rnd = 0; rnd < NR; ++rnd) {
        __syncthreads();
        #pragma unroll
        for (int i = 0; i < 4; ++i) {
            *(bf16x8*)(Ks + (krow + i * 32) * 72 + kcc * 8) = kr[i];
            *(bf16x8*)(Vs + (vd + i * 16) * 136 + vck * 8) = vr[i];
        }
        __syncthreads();
        if (rnd + 1 < NR) {
            int n0k = (rnd + 1) * 128;
            #pragma unroll
            for (int i = 0; i < 4; ++i) {
                int gk = n0k + krow + i * 32;
                kr[i] = *(const bf16x8*)(kb + (rowbase + gk) * qs + h * HD + kcc * 8);
                vr[i] = *(const bf16x8*)(vtb + (size_t)(vd + i * 16) * TPAD + n0k + vck * 8);
            }
        }

        #pragma unroll
        for (int p = 0; p < 2; ++p) {
            int kb0 = p * 64;
            f32x4 s[4] = {};
            #pragma unroll
            for (int ni = 0; ni < 4; ++ni) {
                const unsigned short* kfp = Ks + (kb0 + ni * 16 + ml) * 72 + quad * 8;
                bf16x8 kf0 = *(const bf16x8*)kfp;
                bf16x8 kf1 = *(const bf16x8*)(kfp + 32);
                s[ni] = __builtin_amdgcn_mfma_f32_16x16x32_bf16(qf0, kf0, s[ni], 0, 0, 0);
                s[ni] = __builtin_amdgcn_mfma_f32_16x16x32_bf16(qf1, kf1, s[ni], 0, 0, 0);
            }
            // all staged keys are < 1024 < T: no validity predicate needed
            #pragma unroll
            for (int ni = 0; ni < 4; ++ni) {
                #pragma unroll
                for (int r = 0; r < 4; ++r) {
                    float pv = __expf(s[ni][r] * 0.125f);
                    s[ni][r] = pv;
                    lrow[r] += pv;
                }
            }
            unsigned short* pw = Ps[w];
            #pragma unroll
            for (int r = 0; r < 4; ++r)
                #pragma unroll
                for (int ni = 0; ni < 4; ++ni)
                    pw[(quad * 4 + r) * 72 + ((ni * 16 + ml) ^ (quad << 4))] = f2bf(s[ni][r]);
            int sw = ((ml >> 2) & 3) << 4;
            #pragma unroll
            for (int kc = 0; kc < 2; ++kc) {
                bf16x8 pf = *(const bf16x8*)(pw + ml * 72 + ((kc * 32 + quad * 8) ^ sw));
                #pragma unroll
                for (int ni = 0; ni < 4; ++ni) {
                    bf16x8 vf = *(const bf16x8*)(Vs + (ni * 16 + ml) * 136 + kb0 + kc * 32 + quad * 8);
                    oacc[ni] = __builtin_amdgcn_mfma_f32_16x16x32_bf16(pf, vf, oacc[ni], 0, 0, 0);
                }
            }
        }
    }

    #pragma unroll
    for (int r = 0; r < 4; ++r) {
        #pragma unroll
        for (int off = 1; off < 16; off <<= 1)
            lrow[r] += __shfl_xor(lrow[r], off);
    }

    // ---- tail: key t = 1024 (rank-1 update, no MFMA round) ----
    {
        const unsigned short* kp = kb + (rowbase + SEQ) * qs + h * HD + quad * 8;
        bf16x8 kf0 = *(const bf16x8*)kp;
        bf16x8 kf1 = *(const bf16x8*)(kp + 32);
        float dot = 0.f;
        #pragma unroll
        for (int j = 0; j < 8; ++j) {
            dot += bf2f((unsigned short)qf0[j]) * bf2f((unsigned short)kf0[j]);
            dot += bf2f((unsigned short)qf1[j]) * bf2f((unsigned short)kf1[j]);
        }
        dot += __shfl_xor(dot, 16);
        dot += __shfl_xor(dot, 32);          // every lane now holds the full dot for q-row ml
        float pe = __expf(dot * 0.125f);
        float vv[4];
        #pragma unroll
        for (int ni = 0; ni < 4; ++ni)
            vv[ni] = bf2f(vtb[(size_t)(ni * 16 + ml) * TPAD + SEQ]);
        #pragma unroll
        for (int r = 0; r < 4; ++r) {
            float pr = __shfl(pe, quad * 4 + r);
            lrow[r] += pr;
            #pragma unroll
            for (int ni = 0; ni < 4; ++ni)
                oacc[ni][r] += pr * vv[ni];
        }
    }

    #pragma unroll
    for (int r = 0; r < 4; ++r) {
        int grow = t0 + w * 16 + quad * 4 + r;
        if (grow >= T) continue;
        float inv = 1.f / lrow[r];
        unsigned short* op = ob + (rowbase + grow) * DM + h * HD;
        #pragma unroll
        for (int ni = 0; ni < 4; ++ni)
            op[ni * 16 + ml] = f2bf(oacc[ni][r] * inv);
    }
}

// ---------------------------------------------------------------------------
// Encoder: 8 rows per block, W_enc held in registers per k-step and reused
// across rows (L2 traffic 533 MB -> 67 MB). Writes fp32 h and bf16 shadow hb.
// ---------------------------------------------------------------------------
#define ENC_RPB 8
__global__ __launch_bounds__(256) void encoder_kernel(
    const float* __restrict__ x, const float* __restrict__ W_enc,
    const float* __restrict__ b_enc, const float* __restrict__ cls_tok,
    const float* __restrict__ pos_emb, float* __restrict__ h,
    unsigned short* __restrict__ hb)
{
    int r0 = blockIdx.x * ENC_RPB;
    int tid = threadIdx.x;
    __shared__ float xs[ENC_RPB][NTOK + 1];
    for (int i = tid; i < ENC_RPB * NTOK; i += 256) {
        int rr = i / NTOK, c = i % NTOK;
        int row = r0 + rr;
        float v = 0.f;
        if (row < ROWS) {
            int b = row / T, tt = row % T;
            if (tt > 0)
                v = x[((size_t)b * SEQ + (tt - 1)) * NTOK + c];
        }
        xs[rr][c] = v;
    }
    __syncthreads();
    #pragma unroll
    for (int rep = 0; rep < 2; ++rep) {
        int d = tid + rep * 256;
        float acc[ENC_RPB];
        #pragma unroll
        for (int rr = 0; rr < ENC_RPB; ++rr) acc[rr] = 0.f;
        for (int kx = 0; kx < NTOK; ++kx) {
            float wv = W_enc[kx * DM + d];
            #pragma unroll
            for (int rr = 0; rr < ENC_RPB; ++rr)
                acc[rr] += xs[rr][kx] * wv;
        }
        float be = b_enc[d];
        float ct = cls_tok[d];
        #pragma unroll
        for (int rr = 0; rr < ENC_RPB; ++rr) {
            int row = r0 + rr;
            if (row < ROWS) {
                int b = row / T, tt = row % T;
                float res;
                if (tt == 0) res = ct + pos_emb[d];
                else         res = acc[rr] + be + pos_emb[(size_t)tt * DM + d];
                h[(size_t)row * DM + d]  = res;
                hb[(size_t)row * DM + d] = f2bf(res);
            }
        }
    }
}

// ---------------------------------------------------------------------------
// Fused residual(+already-atomically-accumulated projections) + bias +
// LayerNorm, wave-per-row. Partials loop removed (sk now atomicAdds into h).
// ---------------------------------------------------------------------------
__global__ __launch_bounds__(256) void add_lnp_kernel(
    float* __restrict__ h,
    const float* __restrict__ bias, const float* __restrict__ g,
    const float* __restrict__ be, unsigned short* __restrict__ hb)
{
    int w = threadIdx.x >> 6, l = threadIdx.x & 63;
    int row = blockIdx.x * 4 + w;
    if (row >= ROWS) return;
    float* hp = h + (size_t)row * DM + l * 8;
    unsigned short* hbp = hb + (size_t)row * DM + l * 8;
    float4 a0 = *(const float4*)(hp);
    float4 a1 = *(const float4*)(hp + 4);
    float4 b0 = *(const float4*)(bias + l * 8);
    float4 b1 = *(const float4*)(bias + l * 8 + 4);
    float v[8] = {a0.x + b0.x, a0.y + b0.y, a0.z + b0.z, a0.w + b0.w,
                  a1.x + b1.x, a1.y + b1.y, a1.z + b1.z, a1.w + b1.w};
    float s = 0.f;
    #pragma unroll
    for (int i = 0; i < 8; ++i) s += v[i];
    #pragma unroll
    for (int off = 1; off < 64; off <<= 1) s += __shfl_xor(s, off);
    float mean = s * (1.f / DM);
    float sq = 0.f;
    #pragma unroll
    for (int i = 0; i < 8; ++i) { v[i] -= mean; sq += v[i] * v[i]; }
    #pragma unroll
    for (int off = 1; off < 64; off <<= 1) sq += __shfl_xor(sq, off);
    float inv = rsqrtf(sq * (1.f / DM) + 1e-5f);
    float4 g0 = *(const float4*)(g + l * 8);
    float4 g1 = *(const float4*)(g + l * 8 + 4);
    float4 e0 = *(const float4*)(be + l * 8);
    float4 e1 = *(const float4*)(be + l * 8 + 4);
    float o[8];
    o[0] = v[0]*inv*g0.x + e0.x; o[1] = v[1]*inv*g0.y + e0.y;
    o[2] = v[2]*inv*g0.z + e0.z; o[3] = v[3]*inv*g0.w + e0.w;
    o[4] = v[4]*inv*g1.x + e1.x; o[5] = v[5]*inv*g1.y + e1.y;
    o[6] = v[6]*inv*g1.z + e1.z; o[7] = v[7]*inv*g1.w + e1.w;
    *(float4*)(hp)     = make_float4(o[0], o[1], o[2], o[3]);
    *(float4*)(hp + 4) = make_float4(o[4], o[5], o[6], o[7]);
    ushort4 p0 = {f2bf(o[0]), f2bf(o[1]), f2bf(o[2]), f2bf(o[3])};
    ushort4 p1 = {f2bf(o[4]), f2bf(o[5]), f2bf(o[6]), f2bf(o[7])};
    *(ushort4*)(hbp)     = p0;
    *(ushort4*)(hbp + 4) = p1;
}

// ---------------------------------------------------------------------------
// Fused decoder: one block per batch. cls @ Wd1 + bd1, then @ Wd2 + bd2.
// ---------------------------------------------------------------------------
__global__ __launch_bounds__(256) void dec_kernel(
    const float* __restrict__ h, const float* __restrict__ Wd1,
    const float* __restrict__ bd1, const float* __restrict__ Wd2,
    const float* __restrict__ bd2, float* __restrict__ out)
{
    int b = blockIdx.x;
    int tid = threadIdx.x;
    __shared__ float cs[DM];
    __shared__ float t1s[MLPDIM];
    const float* cls = h + (size_t)b * T * DM;
    cs[tid]       = cls[tid];
    cs[tid + 256] = cls[tid + 256];
    __syncthreads();
    float acc = bd1[tid];
    for (int kx = 0; kx < DM; ++kx)
        acc += cs[kx] * Wd1[(size_t)kx * MLPDIM + tid];
    t1s[tid] = acc;
    __syncthreads();
    if (tid < NCLS) {
        float a2 = bd2[tid];
        for (int kx = 0; kx < MLPDIM; ++kx) a2 += t1s[kx] * Wd2[kx * NCLS + tid];
        out[b * NCLS + tid] = a2;
    }
}

// ---------------------------------------------------------------------------
// GAT: one 64-thread block per graph. Inner dims of hb/o1 padded 64->65 so
// reduction lanes (distinct n at fixed f) land on distinct banks (65 % 32 = 1).
// ---------------------------------------------------------------------------
__global__ __launch_bounds__(64) void gat_kernel(
    const float* __restrict__ x, const int* __restrict__ adj,
    const float* __restrict__ Wg, const float* __restrict__ ag,
    const float* __restrict__ Wgo, const float* __restrict__ ago,
    float* __restrict__ out)
{
    int g = blockIdx.x;
    int s = g / 5, jj = g % 5;
    int tid = threadIdx.x;
    __shared__ float xs[5][3];
    __shared__ int adjs[25];
    __shared__ float hb[GH][5][GHID + 1];
    __shared__ float o1[GH][5][GHID + 1];
    __shared__ float srcb[GH][5], dstb[GH][5];
    __shared__ float attb[GH][5][5];
    __shared__ float h2[5][5], src2[5], dst2[5], att2[5][5], o2[5][5];

    if (tid < 15) { int n = tid / 3, c = tid % 3;
        xs[n][c] = x[(size_t)n * SEQ * NTOK + (size_t)s * NTOK + jj * 3 + c]; }
    if (tid < 25) adjs[tid] = adj[tid];
    __syncthreads();

    #pragma unroll
    for (int hh = 0; hh < GH; ++hh)
        #pragma unroll
        for (int n = 0; n < 5; ++n)
            hb[hh][n][tid] = xs[n][0] * Wg[hh * 192 + tid]
                           + xs[n][1] * Wg[hh * 192 + 64 + tid]
                           + xs[n][2] * Wg[hh * 192 + 128 + tid];
    __syncthreads();

    if (tid < 15) { int hh = tid / 5, n = tid % 5; float a = 0.f;
        for (int f = 0; f < GHID; ++f) a += hb[hh][n][f] * ag[hh * 128 + f];
        srcb[hh][n] = a;
    } else if (tid >= 32 && tid < 47) { int t2 = tid - 32; int hh = t2 / 5, n = t2 % 5; float a = 0.f;
        for (int f = 0; f < GHID; ++f) a += hb[hh][n][f] * ag[hh * 128 + 64 + f];
        dstb[hh][n] = a;
    }
    __syncthreads();

    if (tid < 15) { int hh = tid / 5, i = tid % 5;
        float e[5]; float mx = -1e30f;
        #pragma unroll
        for (int j2 = 0; j2 < 5; ++j2) {
            float ev = srcb[hh][i] + dstb[hh][j2];
            ev = ev > 0.f ? ev : 0.2f * ev;
            e[j2] = ev;
            if (adjs[i * 5 + j2] && ev > mx) mx = ev;
        }
        float sum = 0.f;
        #pragma unroll
        for (int j2 = 0; j2 < 5; ++j2) {
            float p = adjs[i * 5 + j2] ? expf(e[j2] - mx) : 0.f;
            e[j2] = p; sum += p;
        }
        float inv = 1.f / sum;
        #pragma unroll
        for (int j2 = 0; j2 < 5; ++j2) attb[hh][i][j2] = e[j2] * inv;
    }
    __syncthreads();

    #pragma unroll
    for (int hh = 0; hh < GH; ++hh)
        #pragma unroll
        for (int n = 0; n < 5; ++n) {
            float a = 0.f;
            #pragma unroll
            for (int j2 = 0; j2 < 5; ++j2) a += attb[hh][n][j2] * hb[hh][j2][tid];
            o1[hh][n][tid] = a > 0.f ? a : expm1f(a);
        }
    __syncthreads();

    if (tid < 25) { int n = tid / 5, m = tid % 5; float a = 0.f;
        for (int hh = 0; hh < GH; ++hh)
            for (int f = 0; f < GHID; ++f)
                a += o1[hh][n][f] * Wgo[(hh * GHID + f) * GCLS + m];
        h2[n][m] = a;
    }
    __syncthreads();

    if (tid < 5) { float a = 0.f;
        for (int m = 0; m < GCLS; ++m) a += h2[tid][m] * ago[m];
        src2[tid] = a;
    } else if (tid >= 8 && tid < 13) { int n = tid - 8; float a = 0.f;
        for (int m = 0; m < GCLS; ++m) a += h2[n][m] * ago[GCLS + m];
        dst2[n] = a;
    }
    __syncthreads();

    if (tid < 5) { int i = tid;
        float e[5]; float mx = -1e30f;
        #pragma unroll
        for (int j2 = 0; j2 < 5; ++j2) {
            float ev = src2[i] + dst2[j2];
            ev = ev > 0.f ? ev : 0.2f * ev;
            e[j2] = ev;
            if (adjs[i * 5 + j2] && ev > mx) mx = ev;
        }
        float sum = 0.f;
        #pragma unroll
        for (int j2 = 0; j2 < 5; ++j2) {
            float p = adjs[i * 5 + j2] ? expf(e[j2] - mx) : 0.f;
            e[j2] = p; sum += p;
        }
        float inv = 1.f / sum;
        #pragma unroll
        for (int j2 = 0; j2 < 5; ++j2) att2[i][j2] = e[j2] * inv;
    }
    __syncthreads();

    if (tid < 25) { int n = tid / 5, m = tid % 5; float a = 0.f;
        #pragma unroll
        for (int j2 = 0; j2 < 5; ++j2) a += att2[n][j2] * h2[j2][m];
        o2[n][m] = a > 0.f ? a : expm1f(a);
    }
    __syncthreads();

    if (tid < 5) { int n = tid;
        float mx = o2[n][0];
        #pragma unroll
        for (int m = 1; m < GCLS; ++m) mx = fmaxf(mx, o2[n][m]);
        float sum = 0.f;
        #pragma unroll
        for (int m = 0; m < GCLS; ++m) sum += expf(o2[n][m] - mx);
        float ls = logf(sum);
        #pragma unroll
        for (int m = 0; m < GCLS; ++m)
            out[(size_t)g * 25 + n * 5 + m] = o2[n][m] - mx - ls;
    }
}

// ---------------------------------------------------------------------------
// Launch
// ---------------------------------------------------------------------------
extern "C" void kernel_launch(void* const* d_in, const int* in_sizes, int n_in,
                              void* d_out, int out_size, void* d_ws, size_t ws_size,
                              hipStream_t stream)
{
    const float* x       = (const float*)d_in[0];
    const int*   adj     = (const int*)  d_in[1];
    const float* W_enc   = (const float*)d_in[2];
    const float* b_enc   = (const float*)d_in[3];
    const float* cls_tok = (const float*)d_in[4];
    const float* pos_emb = (const float*)d_in[5];
    const float* Wq = (const float*)d_in[6];
    const float* bq = (const float*)d_in[7];
    const float* Wk = (const float*)d_in[8];
    const float* bk = (const float*)d_in[9];
    const float* Wv = (const float*)d_in[10];
    const float* bv = (const float*)d_in[11];
    const float* Wo = (const float*)d_in[12];
    const float* bo = (const float*)d_in[13];
    const float* W1 = (const float*)d_in[14];
    const float* b1 = (const float*)d_in[15];
    const float* W2 = (const float*)d_in[16];
    const float* b2 = (const float*)d_in[17];
    const float* g1 = (const float*)d_in[18];
    const float* be1= (const float*)d_in[19];
    const float* g2 = (const float*)d_in[20];
    const float* be2= (const float*)d_in[21];
    const float* Wd1= (const float*)d_in[22];
    const float* bd1= (const float*)d_in[23];
    const float* Wd2= (const float*)d_in[24];
    const float* bd2= (const float*)d_in[25];
    const float* Wg = (const float*)d_in[26];
    const float* ag = (const float*)d_in[27];
    const float* Wgo= (const float*)d_in[28];
    const float* ago= (const float*)d_in[29];
    float* out = (float*)d_out;

    // workspace layout (~91 MB)
    float* ws = (float*)d_ws;
    float* h = ws;
    unsigned short* hb   = (unsigned short*)(h + (size_t)MP * DM);
    unsigned short* qkvb = hb + (size_t)MP * DM;
    unsigned short* ob   = qkvb + (size_t)MP * QKVN;
    unsigned short* f1b  = qkvb;                    // alias qkvb+ob
    unsigned short* Wqkvt= ob + (size_t)MP * DM;
    unsigned short* Wot  = Wqkvt + (size_t)4 * QKVN * DM;
    unsigned short* W1t  = Wot + (size_t)4 * DM * DM;
    unsigned short* W2t  = W1t + (size_t)4 * DM * DFF;
    float* bqkv = (float*)(W2t + (size_t)4 * DFF * DM);
    float* dpart = bqkv + 4 * QKVN;
    unsigned short* vt = (unsigned short*)(dpart + NBATCH * 8 * MLPDIM);  // [40][64][TPAD]

    setup_kernel<<<12292, 256, 0, stream>>>(Wq, Wk, Wv, Wo, W1, W2, bq, bk, bv,
                                            Wqkvt, Wot, W1t, W2t, bqkv);

    gat_kernel<<<NGRAPH, 64, 0, stream>>>(x, adj, Wg, ag, Wgo, ago, out + NBATCH * NCLS);
    encoder_kernel<<<(ROWS + ENC_RPB - 1) / ENC_RPB, 256, 0, stream>>>(
        x, W_enc, b_enc, cls_tok, pos_emb, h, hb);

    dim3 gqkv (QKVN / 128, MP / 128);        // (12, 41)
    dim3 g2048(DFF / 128, MP / 128);         // (16, 41)
    dim3 gWo  (DM / 128, MP / 128, 2);       // split-K=2, atomic into h
    dim3 gW2  (DM / 128, MP / 128, 4);       // split-K=4, atomic into h
    dim3 gAttn(17, NBATCH * NHEAD);          // 17 q-tiles x 40 bh
    dim3 gVt  (17, NBATCH * NHEAD);          // 17 key-tiles x 40 bh (t<1088)
    int gLN = (ROWS + 3) / 4;

    for (int i = 0; i < 4; ++i) {
        gemm_mfma<<<gqkv, 256, 0, stream>>>(hb, Wqkvt + (size_t)i*QKVN*DM, bqkv + i*QKVN, nullptr, qkvb, QKVN, DM, 0);
        vtrans_kernel<<<gVt, 256, 0, stream>>>(qkvb + 1024, vt, QKVN);
        attn_mfma<<<gAttn, 256, 0, stream>>>(qkvb, qkvb + 512, vt, ob, QKVN);
        gemm_mfma_sk<<<gWo, 256, 0, stream>>>(ob, Wot + (size_t)i*DM*DM, h, DM, DM);
        add_lnp_kernel<<<gLN, 256, 0, stream>>>(h, bo + i*DM, g1 + i*DM, be1 + i*DM, hb);
        gemm_mfma<<<g2048, 256, 0, stream>>>(hb,  W1t + (size_t)i*DM*DFF, b1 + i*DFF, nullptr, f1b, DFF, DM, 1);
        gemm_mfma_sk<<<gW2, 256, 0, stream>>>(f1b, W2t + (size_t)i*DM*DFF, h, DM, DFF);
        add_lnp_kernel<<<gLN, 256, 0, stream>>>(h, b2 + i*DM, g2 + i*DM, be2 + i*DM, hb);
    }

    dec_kernel<<<NBATCH, 256, 0, stream>>>(h, Wd1, bd1, Wd2, bd2, out);
}

// Round 8
// 852.605 us; speedup vs baseline: 1.0606x; 1.0606x over previous
//
#include <hip/hip_runtime.h>
#include <hip/hip_bf16.h>
#include <math.h>

// ---------------------------------------------------------------------------
// Model constants
// ---------------------------------------------------------------------------
#define NBATCH 5
#define SEQ    1024
#define T      1025          // SEQ + 1 (cls token)
#define ROWS   (NBATCH * T)  // 5125
#define MP     5248          // ROWS padded to 41*128 for MFMA tiles
#define DM     512
#define DFF    2048
#define NHEAD  8
#define HD     64
#define NTOK   51
#define MLPDIM 256
#define NCLS   7
#define GH     3
#define GHID   64
#define GCLS   5
#define NGRAPH (SEQ * 5)     // 5120
#define QKVN   1536          // fused QKV output width
#define TPAD   1152          // V^T row stride (only t<1025 ever read)

#define ENC_RPB 8
#define PRE_SETUP 12292                  // setup blocks (incl. 4 bias blocks)
#define PRE_GAT   (NGRAPH / 4)           // 1280 blocks, 4 graphs each
#define PRE_ENC   ((ROWS + ENC_RPB - 1) / ENC_RPB)  // 641
#define PRE_TOTAL (PRE_SETUP + PRE_GAT + PRE_ENC)

typedef __attribute__((ext_vector_type(8))) short bf16x8;
typedef __attribute__((ext_vector_type(4))) float f32x4;

#define GM_AS(p)  ((const __attribute__((address_space(1))) void*)(p))
#define LDS_AS(p) ((__attribute__((address_space(3))) void*)(p))

__device__ __forceinline__ unsigned short f2bf(float f) {
    unsigned int u = __float_as_uint(f);
    unsigned int r = (u + 0x7FFFu + ((u >> 16) & 1u)) >> 16;
    return (unsigned short)r;
}
__device__ __forceinline__ float bf2f(unsigned short u) {
    return __uint_as_float((unsigned int)u << 16);
}

// ---------------------------------------------------------------------------
// Fused prelude: setup (weight transposes + bias concat) | GAT | encoder.
// The three are mutually independent; fusing makes their durations max()
// instead of sum() and drops 2 launch gaps. Per-role code is identical to
// the previous separate kernels (bit-identical numerics); GAT is repacked
// 4 graphs/block (one per wave) so all roles share blockDim=256.
// ---------------------------------------------------------------------------
struct GatSmem {
    float xs[4][5][3];
    int   adjs[25];
    float gb[4][GH][5][GHID + 1];
    float o1[4][GH][5][GHID + 1];
    float srcb[4][GH][5], dstb[4][GH][5];
    float attb[4][GH][5][5];
    float h2[4][5][5], src2[4][5], dst2[4][5], att2[4][5][5], o2[4][5][5];
};
struct SetupSmem { float tile[32][33]; };
struct EncSmem   { float xs[ENC_RPB][NTOK + 1]; };

__global__ __launch_bounds__(256) void prelude_kernel(
    // gat
    const float* __restrict__ x, const int* __restrict__ adj,
    const float* __restrict__ Wg, const float* __restrict__ ag,
    const float* __restrict__ Wgo, const float* __restrict__ ago,
    float* __restrict__ gat_out,
    // setup
    const float* __restrict__ Wq, const float* __restrict__ Wk,
    const float* __restrict__ Wv, const float* __restrict__ Wo_,
    const float* __restrict__ W1, const float* __restrict__ W2,
    const float* __restrict__ bq, const float* __restrict__ bk,
    const float* __restrict__ bv,
    unsigned short* __restrict__ Wqkvt, unsigned short* __restrict__ Wot,
    unsigned short* __restrict__ W1t, unsigned short* __restrict__ W2t,
    float* __restrict__ bqkv,
    // encoder
    const float* __restrict__ W_enc, const float* __restrict__ b_enc,
    const float* __restrict__ cls_tok, const float* __restrict__ pos_emb,
    float* __restrict__ h, unsigned short* __restrict__ hb)
{
    __shared__ __align__(16) char smem_raw[sizeof(GatSmem)];
    int id = blockIdx.x;
    int tid = threadIdx.x;

    if (id < PRE_SETUP) {
        // ---------------- setup role ----------------
        if (id >= 12288) {           // bias concat: 4 blocks, one per layer
            int i = id - 12288;
            #pragma unroll
            for (int rep = 0; rep < 2; ++rep) {
                int t = tid + rep * 256;
                bqkv[i * QKVN + t]        = bq[i * DM + t];
                bqkv[i * QKVN + 512 + t]  = bk[i * DM + t];
                bqkv[i * QKVN + 1024 + t] = bv[i * DM + t];
            }
            return;
        }
        const float* W; unsigned short* Wt; int K, N, z, bx, by; long dstride;
        if (id < 4096) {             // Wq/Wk/Wv/Wo: 512x512
            int g = id >> 10, lid = id & 1023;
            K = DM; N = DM;
            z = lid >> 8; int r2 = lid & 255; by = r2 >> 4; bx = r2 & 15;
            if (g < 3) { W = (g == 0) ? Wq : (g == 1) ? Wk : Wv;
                         Wt = Wqkvt + (size_t)g * DM * DM; dstride = (long)QKVN * DM; }
            else       { W = Wo_; Wt = Wot; dstride = (long)DM * DM; }
        } else if (id < 8192) {      // W1: K=512, N=2048
            int lid = id - 4096;
            K = DM; N = DFF;
            z = lid >> 10; int r2 = lid & 1023; by = r2 >> 6; bx = r2 & 63;
            W = W1; Wt = W1t; dstride = (long)DM * DFF;
        } else {                     // W2: K=2048, N=512
            int lid = id - 8192;
            K = DFF; N = DM;
            z = lid >> 10; int r2 = lid & 1023; by = r2 >> 4; bx = r2 & 15;
            W = W2; Wt = W2t; dstride = (long)DFF * DM;
        }
        const float* Wm = W + (size_t)z * K * N;
        unsigned short* Wo2 = Wt + (size_t)z * dstride;
        SetupSmem& ss = *reinterpret_cast<SetupSmem*>(smem_raw);
        int bX = bx * 32, bY = by * 32;
        int tx = tid & 31, ty = tid >> 5;
        #pragma unroll
        for (int i = 0; i < 32; i += 8)
            ss.tile[ty + i][tx] = Wm[(size_t)(bY + ty + i) * N + bX + tx];
        __syncthreads();
        #pragma unroll
        for (int i = 0; i < 32; i += 8)
            Wo2[(size_t)(bX + ty + i) * K + bY + tx] = f2bf(ss.tile[tx][ty + i]);
        return;
    }

    if (id < PRE_SETUP + PRE_GAT) {
        // ---------------- GAT role: 4 graphs per block, one per wave -------
        GatSmem& gs = *reinterpret_cast<GatSmem*>(smem_raw);
        int w = tid >> 6, lane = tid & 63;
        int g = (id - PRE_SETUP) * 4 + w;
        int s = g / 5, jj = g % 5;
        if (tid < 25) gs.adjs[tid] = adj[tid];
        if (lane < 15) { int n = lane / 3, c = lane % 3;
            gs.xs[w][n][c] = x[(size_t)n * SEQ * NTOK + (size_t)s * NTOK + jj * 3 + c]; }
        __syncthreads();

        #pragma unroll
        for (int hh = 0; hh < GH; ++hh)
            #pragma unroll
            for (int n = 0; n < 5; ++n)
                gs.gb[w][hh][n][lane] = gs.xs[w][n][0] * Wg[hh * 192 + lane]
                                      + gs.xs[w][n][1] * Wg[hh * 192 + 64 + lane]
                                      + gs.xs[w][n][2] * Wg[hh * 192 + 128 + lane];
        __syncthreads();

        if (lane < 15) { int hh = lane / 5, n = lane % 5; float a = 0.f;
            for (int f = 0; f < GHID; ++f) a += gs.gb[w][hh][n][f] * ag[hh * 128 + f];
            gs.srcb[w][hh][n] = a;
        } else if (lane >= 32 && lane < 47) { int t2 = lane - 32; int hh = t2 / 5, n = t2 % 5; float a = 0.f;
            for (int f = 0; f < GHID; ++f) a += gs.gb[w][hh][n][f] * ag[hh * 128 + 64 + f];
            gs.dstb[w][hh][n] = a;
        }
        __syncthreads();

        if (lane < 15) { int hh = lane / 5, i = lane % 5;
            float e[5]; float mx = -1e30f;
            #pragma unroll
            for (int j2 = 0; j2 < 5; ++j2) {
                float ev = gs.srcb[w][hh][i] + gs.dstb[w][hh][j2];
                ev = ev > 0.f ? ev : 0.2f * ev;
                e[j2] = ev;
                if (gs.adjs[i * 5 + j2] && ev > mx) mx = ev;
            }
            float sum = 0.f;
            #pragma unroll
            for (int j2 = 0; j2 < 5; ++j2) {
                float p = gs.adjs[i * 5 + j2] ? expf(e[j2] - mx) : 0.f;
                e[j2] = p; sum += p;
            }
            float inv = 1.f / sum;
            #pragma unroll
            for (int j2 = 0; j2 < 5; ++j2) gs.attb[w][hh][i][j2] = e[j2] * inv;
        }
        __syncthreads();

        #pragma unroll
        for (int hh = 0; hh < GH; ++hh)
            #pragma unroll
            for (int n = 0; n < 5; ++n) {
                float a = 0.f;
                #pragma unroll
                for (int j2 = 0; j2 < 5; ++j2) a += gs.attb[w][hh][n][j2] * gs.gb[w][hh][j2][lane];
                gs.o1[w][hh][n][lane] = a > 0.f ? a : expm1f(a);
            }
        __syncthreads();

        if (lane < 25) { int n = lane / 5, m = lane % 5; float a = 0.f;
            for (int hh = 0; hh < GH; ++hh)
                for (int f = 0; f < GHID; ++f)
                    a += gs.o1[w][hh][n][f] * Wgo[(hh * GHID + f) * GCLS + m];
            gs.h2[w][n][m] = a;
        }
        __syncthreads();

        if (lane < 5) { float a = 0.f;
            for (int m = 0; m < GCLS; ++m) a += gs.h2[w][lane][m] * ago[m];
            gs.src2[w][lane] = a;
        } else if (lane >= 8 && lane < 13) { int n = lane - 8; float a = 0.f;
            for (int m = 0; m < GCLS; ++m) a += gs.h2[w][n][m] * ago[GCLS + m];
            gs.dst2[w][n] = a;
        }
        __syncthreads();

        if (lane < 5) { int i = lane;
            float e[5]; float mx = -1e30f;
            #pragma unroll
            for (int j2 = 0; j2 < 5; ++j2) {
                float ev = gs.src2[w][i] + gs.dst2[w][j2];
                ev = ev > 0.f ? ev : 0.2f * ev;
                e[j2] = ev;
                if (gs.adjs[i * 5 + j2] && ev > mx) mx = ev;
            }
            float sum = 0.f;
            #pragma unroll
            for (int j2 = 0; j2 < 5; ++j2) {
                float p = gs.adjs[i * 5 + j2] ? expf(e[j2] - mx) : 0.f;
                e[j2] = p; sum += p;
            }
            float inv = 1.f / sum;
            #pragma unroll
            for (int j2 = 0; j2 < 5; ++j2) gs.att2[w][i][j2] = e[j2] * inv;
        }
        __syncthreads();

        if (lane < 25) { int n = lane / 5, m = lane % 5; float a = 0.f;
            #pragma unroll
            for (int j2 = 0; j2 < 5; ++j2) a += gs.att2[w][n][j2] * gs.h2[w][j2][m];
            gs.o2[w][n][m] = a > 0.f ? a : expm1f(a);
        }
        __syncthreads();

        if (lane < 5) { int n = lane;
            float mx = gs.o2[w][n][0];
            #pragma unroll
            for (int m = 1; m < GCLS; ++m) mx = fmaxf(mx, gs.o2[w][n][m]);
            float sum = 0.f;
            #pragma unroll
            for (int m = 0; m < GCLS; ++m) sum += expf(gs.o2[w][n][m] - mx);
            float ls = logf(sum);
            #pragma unroll
            for (int m = 0; m < GCLS; ++m)
                gat_out[(size_t)g * 25 + n * 5 + m] = gs.o2[w][n][m] - mx - ls;
        }
        return;
    }

    // ---------------- encoder role ----------------
    {
        EncSmem& es = *reinterpret_cast<EncSmem*>(smem_raw);
        int r0 = (id - PRE_SETUP - PRE_GAT) * ENC_RPB;
        for (int i = tid; i < ENC_RPB * NTOK; i += 256) {
            int rr = i / NTOK, c = i % NTOK;
            int row = r0 + rr;
            float v = 0.f;
            if (row < ROWS) {
                int b = row / T, tt = row % T;
                if (tt > 0)
                    v = x[((size_t)b * SEQ + (tt - 1)) * NTOK + c];
            }
            es.xs[rr][c] = v;
        }
        __syncthreads();
        #pragma unroll
        for (int rep = 0; rep < 2; ++rep) {
            int d = tid + rep * 256;
            float acc[ENC_RPB];
            #pragma unroll
            for (int rr = 0; rr < ENC_RPB; ++rr) acc[rr] = 0.f;
            for (int kx = 0; kx < NTOK; ++kx) {
                float wv = W_enc[kx * DM + d];
                #pragma unroll
                for (int rr = 0; rr < ENC_RPB; ++rr)
                    acc[rr] += es.xs[rr][kx] * wv;
            }
            float be = b_enc[d];
            float ct = cls_tok[d];
            #pragma unroll
            for (int rr = 0; rr < ENC_RPB; ++rr) {
                int row = r0 + rr;
                if (row < ROWS) {
                    int b = row / T, tt = row % T;
                    float res;
                    if (tt == 0) res = ct + pos_emb[d];
                    else         res = acc[rr] + be + pos_emb[(size_t)tt * DM + d];
                    h[(size_t)row * DM + d]  = res;
                    hb[(size_t)row * DM + d] = f2bf(res);
                }
            }
        }
    }
}

// ---------------------------------------------------------------------------
// bf16 MFMA GEMM: C[M][N] = A[M][K] @ Bt[N][K]^T + bias. 128x128 tile, BK=64.
// ---------------------------------------------------------------------------
__global__ __launch_bounds__(256) void gemm_mfma(
    const unsigned short* __restrict__ A, const unsigned short* __restrict__ Bt,
    const float* __restrict__ bias, float* __restrict__ Cf,
    unsigned short* __restrict__ Cb, int N, int K, int relu)
{
    __shared__ unsigned short As[128 * 64];
    __shared__ unsigned short Bs[128 * 64];
    int tid = threadIdx.x;
    int l = tid & 63, w = tid >> 6;
    int wr = w & 1, wc = w >> 1;
    int mlane = l & 15, quad = l >> 4;
    int m0 = blockIdx.y * 128, n0 = blockIdx.x * 128;

    f32x4 acc[4][4] = {};

    for (int k0 = 0; k0 < K; k0 += 64) {
        __syncthreads();
        #pragma unroll
        for (int it = 0; it < 4; ++it) {
            int c = tid + it * 256;
            int row = c >> 3, cc = c & 7;
            const unsigned short* ga = A  + (size_t)(m0 + row) * K + k0 + cc * 8;
            __builtin_amdgcn_global_load_lds(GM_AS(ga), LDS_AS(As + c * 8), 16, 0, 0);
            const unsigned short* gb = Bt + (size_t)(n0 + row) * K + k0 + cc * 8;
            __builtin_amdgcn_global_load_lds(GM_AS(gb), LDS_AS(Bs + c * 8), 16, 0, 0);
        }
        __syncthreads();
        #pragma unroll
        for (int half = 0; half < 2; ++half) {
            int ko = half * 32 + quad * 8;
            bf16x8 afrag[4], bfrag[4];
            #pragma unroll
            for (int mi = 0; mi < 4; ++mi)
                afrag[mi] = *(const bf16x8*)(As + (wr * 64 + mi * 16 + mlane) * 64 + ko);
            #pragma unroll
            for (int ni = 0; ni < 4; ++ni)
                bfrag[ni] = *(const bf16x8*)(Bs + (wc * 64 + ni * 16 + mlane) * 64 + ko);
            #pragma unroll
            for (int mi = 0; mi < 4; ++mi)
                #pragma unroll
                for (int ni = 0; ni < 4; ++ni)
                    acc[mi][ni] = __builtin_amdgcn_mfma_f32_16x16x32_bf16(
                        afrag[mi], bfrag[ni], acc[mi][ni], 0, 0, 0);
        }
    }

    #pragma unroll
    for (int mi = 0; mi < 4; ++mi) {
        #pragma unroll
        for (int r = 0; r < 4; ++r) {
            int gm = m0 + wr * 64 + mi * 16 + quad * 4 + r;
            size_t rowoff = (size_t)gm * N;
            #pragma unroll
            for (int ni = 0; ni < 4; ++ni) {
                int gn = n0 + wc * 64 + ni * 16 + mlane;
                float val = acc[mi][ni][r] + bias[gn];
                if (relu) val = fmaxf(val, 0.f);
                if (Cb) Cb[rowoff + gn] = f2bf(val);
                else    Cf[rowoff + gn] = val;
            }
        }
    }
}

// ---------------------------------------------------------------------------
// Split-K bf16 MFMA GEMM: writes bf16 partials; combined in add_lnp.
// (fp32 atomicAdd variant measured 52us/dispatch: atomic-throughput-bound.)
// ---------------------------------------------------------------------------
__global__ __launch_bounds__(256) void gemm_mfma_sk(
    const unsigned short* __restrict__ A, const unsigned short* __restrict__ Bt,
    unsigned short* __restrict__ part, int N, int K)
{
    __shared__ unsigned short As[128 * 64];
    __shared__ unsigned short Bs[128 * 64];
    int tid = threadIdx.x;
    int l = tid & 63, w = tid >> 6;
    int wr = w & 1, wc = w >> 1;
    int mlane = l & 15, quad = l >> 4;
    int m0 = blockIdx.y * 128, n0 = blockIdx.x * 128;
    int kper = K / gridDim.z;
    int kbeg = blockIdx.z * kper;

    f32x4 acc[4][4] = {};

    for (int k0 = kbeg; k0 < kbeg + kper; k0 += 64) {
        __syncthreads();
        #pragma unroll
        for (int it = 0; it < 4; ++it) {
            int c = tid + it * 256;
            int row = c >> 3, cc = c & 7;
            const unsigned short* ga = A  + (size_t)(m0 + row) * K + k0 + cc * 8;
            __builtin_amdgcn_global_load_lds(GM_AS(ga), LDS_AS(As + c * 8), 16, 0, 0);
            const unsigned short* gb = Bt + (size_t)(n0 + row) * K + k0 + cc * 8;
            __builtin_amdgcn_global_load_lds(GM_AS(gb), LDS_AS(Bs + c * 8), 16, 0, 0);
        }
        __syncthreads();
        #pragma unroll
        for (int half = 0; half < 2; ++half) {
            int ko = half * 32 + quad * 8;
            bf16x8 afrag[4], bfrag[4];
            #pragma unroll
            for (int mi = 0; mi < 4; ++mi)
                afrag[mi] = *(const bf16x8*)(As + (wr * 64 + mi * 16 + mlane) * 64 + ko);
            #pragma unroll
            for (int ni = 0; ni < 4; ++ni)
                bfrag[ni] = *(const bf16x8*)(Bs + (wc * 64 + ni * 16 + mlane) * 64 + ko);
            #pragma unroll
            for (int mi = 0; mi < 4; ++mi)
                #pragma unroll
                for (int ni = 0; ni < 4; ++ni)
                    acc[mi][ni] = __builtin_amdgcn_mfma_f32_16x16x32_bf16(
                        afrag[mi], bfrag[ni], acc[mi][ni], 0, 0, 0);
        }
    }

    unsigned short* pz = part + (size_t)blockIdx.z * MP * N;
    #pragma unroll
    for (int mi = 0; mi < 4; ++mi) {
        #pragma unroll
        for (int r = 0; r < 4; ++r) {
            int gm = m0 + wr * 64 + mi * 16 + quad * 4 + r;
            size_t rowoff = (size_t)gm * N;
            #pragma unroll
            for (int ni = 0; ni < 4; ++ni) {
                int gn = n0 + wc * 64 + ni * 16 + mlane;
                pz[rowoff + gn] = f2bf(acc[mi][ni][r]);
            }
        }
    }
}

// ---------------------------------------------------------------------------
// V transpose per layer: vb rows (b,t) stride qs -> vt[(bh*64+d)][TPAD].
// x-grid = 17 tiles (covers t < 1088; only t < 1025 is ever read).
// ---------------------------------------------------------------------------
__global__ __launch_bounds__(256) void vtrans_kernel(
    const unsigned short* __restrict__ vb, unsigned short* __restrict__ vt, int qs)
{
    __shared__ unsigned short tile[64][72];
    int bh = blockIdx.y;
    int b = bh >> 3, h = bh & 7;
    int t0 = blockIdx.x * 64;
    int tid = threadIdx.x;
    #pragma unroll
    for (int it = 0; it < 2; ++it) {
        int c = tid + it * 256;
        int key = c >> 3, cc = c & 7;
        int gk = t0 + key; if (gk >= T) gk = T - 1;
        *(bf16x8*)(&tile[key][cc * 8]) =
            *(const bf16x8*)(vb + ((size_t)b * T + gk) * qs + h * HD + cc * 8);
    }
    __syncthreads();
    #pragma unroll
    for (int it = 0; it < 2; ++it) {
        int c = tid + it * 256;
        int d = c >> 3, cc = c & 7;
        unsigned short tmp[8];
        #pragma unroll
        for (int j = 0; j < 8; ++j) tmp[j] = tile[cc * 8 + j][d];
        *(bf16x8*)(vt + ((size_t)bh * 64 + d) * TPAD + t0 + cc * 8) = *(bf16x8*)tmp;
    }
}

// ---------------------------------------------------------------------------
// bf16 MFMA flash attention. NR=8 rounds of 128 keys cover t in [0,1024);
// the single remaining key t=1024 is a scalar rank-1 tail.
// Block = 64 queries x (b,h); 4 waves x 16 q — measured local optimum
// (2-wave: 52us occupancy-bound; 8-wave/128q: +12us; setprio: +9us).
// ---------------------------------------------------------------------------
#define AQT 64
#define NR 8    // rounds of 128 keys over [0,1024)
__global__ __launch_bounds__(256) void attn_mfma(
    const unsigned short* __restrict__ qb, const unsigned short* __restrict__ kb,
    const unsigned short* __restrict__ vt, unsigned short* __restrict__ ob,
    int qs)
{
    __shared__ unsigned short Ks[128 * 72];    // [key][72]
    __shared__ unsigned short Vs[64 * 136];    // [d][136] keys contiguous
    __shared__ unsigned short Ps[4][16 * 72];
    int bh = blockIdx.y;
    int b = bh >> 3, h = bh & 7;
    int t0 = blockIdx.x * AQT;
    int tid = threadIdx.x;
    int l = tid & 63, w = tid >> 6;
    int ml = l & 15, quad = l >> 4;
    size_t rowbase = (size_t)b * T;
    const unsigned short* vtb = vt + (size_t)bh * 64 * TPAD;

    int qrow = t0 + w * 16 + ml; if (qrow >= T) qrow = T - 1;
    const unsigned short* qp = qb + (rowbase + qrow) * qs + h * HD + quad * 8;
    bf16x8 qf0 = *(const bf16x8*)qp;
    bf16x8 qf1 = *(const bf16x8*)(qp + 32);

    int krow = tid >> 3, kcc = tid & 7;
    int vd   = tid >> 4, vck = tid & 15;

    f32x4 oacc[4] = {};
    float lrow[4] = {0.f, 0.f, 0.f, 0.f};

    bf16x8 kr[4], vr[4];
    #pragma unroll
    for (int i = 0; i < 4; ++i) {
        int gk = krow + i * 32;
        kr[i] = *(const bf16x8*)(kb + (rowbase + gk) * qs + h * HD + kcc * 8);
        vr[i] = *(const bf16x8*)(vtb + (size_t)(vd + i * 16) * TPAD + vck * 8);
    }

    for (int rnd = 0; rnd < NR; ++rnd) {
        __syncthreads();
        #pragma unroll
        for (int i = 0; i < 4; ++i) {
            *(bf16x8*)(Ks + (krow + i * 32) * 72 + kcc * 8) = kr[i];
            *(bf16x8*)(Vs + (vd + i * 16) * 136 + vck * 8) = vr[i];
        }
        __syncthreads();
        if (rnd + 1 < NR) {
            int n0k = (rnd + 1) * 128;
            #pragma unroll
            for (int i = 0; i < 4; ++i) {
                int gk = n0k + krow + i * 32;
                kr[i] = *(const bf16x8*)(kb + (rowbase + gk) * qs + h * HD + kcc * 8);
                vr[i] = *(const bf16x8*)(vtb + (size_t)(vd + i * 16) * TPAD + n0k + vck * 8);
            }
        }

        #pragma unroll
        for (int p = 0; p < 2; ++p) {
            int kb0 = p * 64;
            f32x4 s[4] = {};
            #pragma unroll
            for (int ni = 0; ni < 4; ++ni) {
                const unsigned short* kfp = Ks + (kb0 + ni * 16 + ml) * 72 + quad * 8;
                bf16x8 kf0 = *(const bf16x8*)kfp;
                bf16x8 kf1 = *(const bf16x8*)(kfp + 32);
                s[ni] = __builtin_amdgcn_mfma_f32_16x16x32_bf16(qf0, kf0, s[ni], 0, 0, 0);
                s[ni] = __builtin_amdgcn_mfma_f32_16x16x32_bf16(qf1, kf1, s[ni], 0, 0, 0);
            }
            // all staged keys are < 1024 < T: no validity predicate needed
            #pragma unroll
            for (int ni = 0; ni < 4; ++ni) {
                #pragma unroll
                for (int r = 0; r < 4; ++r) {
                    float pv = __expf(s[ni][r] * 0.125f);
                    s[ni][r] = pv;
                    lrow[r] += pv;
                }
            }
            unsigned short* pw = Ps[w];
            #pragma unroll
            for (int r = 0; r < 4; ++r)
                #pragma unroll
                for (int ni = 0; ni < 4; ++ni)
                    pw[(quad * 4 + r) * 72 + ((ni * 16 + ml) ^ (quad << 4))] = f2bf(s[ni][r]);
            int sw = ((ml >> 2) & 3) << 4;
            #pragma unroll
            for (int kc = 0; kc < 2; ++kc) {
                bf16x8 pf = *(const bf16x8*)(pw + ml * 72 + ((kc * 32 + quad * 8) ^ sw));
                #pragma unroll
                for (int ni = 0; ni < 4; ++ni) {
                    bf16x8 vf = *(const bf16x8*)(Vs + (ni * 16 + ml) * 136 + kb0 + kc * 32 + quad * 8);
                    oacc[ni] = __builtin_amdgcn_mfma_f32_16x16x32_bf16(pf, vf, oacc[ni], 0, 0, 0);
                }
            }
        }
    }

    #pragma unroll
    for (int r = 0; r < 4; ++r) {
        #pragma unroll
        for (int off = 1; off < 16; off <<= 1)
            lrow[r] += __shfl_xor(lrow[r], off);
    }

    // ---- tail: key t = 1024 (rank-1 update, no MFMA round) ----
    {
        const unsigned short* kp = kb + (rowbase + SEQ) * qs + h * HD + quad * 8;
        bf16x8 kf0 = *(const bf16x8*)kp;
        bf16x8 kf1 = *(const bf16x8*)(kp + 32);
        float dot = 0.f;
        #pragma unroll
        for (int j = 0; j < 8; ++j) {
            dot += bf2f((unsigned short)qf0[j]) * bf2f((unsigned short)kf0[j]);
            dot += bf2f((unsigned short)qf1[j]) * bf2f((unsigned short)kf1[j]);
        }
        dot += __shfl_xor(dot, 16);
        dot += __shfl_xor(dot, 32);          // every lane now holds the full dot for q-row ml
        float pe = __expf(dot * 0.125f);
        float vv[4];
        #pragma unroll
        for (int ni = 0; ni < 4; ++ni)
            vv[ni] = bf2f(vtb[(size_t)(ni * 16 + ml) * TPAD + SEQ]);
        #pragma unroll
        for (int r = 0; r < 4; ++r) {
            float pr = __shfl(pe, quad * 4 + r);
            lrow[r] += pr;
            #pragma unroll
            for (int ni = 0; ni < 4; ++ni)
                oacc[ni][r] += pr * vv[ni];
        }
    }

    #pragma unroll
    for (int r = 0; r < 4; ++r) {
        int grow = t0 + w * 16 + quad * 4 + r;
        if (grow >= T) continue;
        float inv = 1.f / lrow[r];
        unsigned short* op = ob + (rowbase + grow) * DM + h * HD;
        #pragma unroll
        for (int ni = 0; ni < 4; ++ni)
            op[ni * 16 + ml] = f2bf(oacc[ni][r] * inv);
    }
}

// ---------------------------------------------------------------------------
// Fused (sum of np bf16 partials + bias) residual + LayerNorm, wave-per-row
// ---------------------------------------------------------------------------
__global__ __launch_bounds__(256) void add_lnp_kernel(
    float* __restrict__ h, const unsigned short* __restrict__ part, int np,
    const float* __restrict__ bias, const float* __restrict__ g,
    const float* __restrict__ be, unsigned short* __restrict__ hb)
{
    int w = threadIdx.x >> 6, l = threadIdx.x & 63;
    int row = blockIdx.x * 4 + w;
    if (row >= ROWS) return;
    float* hp = h + (size_t)row * DM + l * 8;
    unsigned short* hbp = hb + (size_t)row * DM + l * 8;
    float4 a0 = *(const float4*)(hp);
    float4 a1 = *(const float4*)(hp + 4);
    float4 b0 = *(const float4*)(bias + l * 8);
    float4 b1 = *(const float4*)(bias + l * 8 + 4);
    float v[8] = {a0.x + b0.x, a0.y + b0.y, a0.z + b0.z, a0.w + b0.w,
                  a1.x + b1.x, a1.y + b1.y, a1.z + b1.z, a1.w + b1.w};
    for (int pp = 0; pp < np; ++pp) {
        const unsigned short* prp = part + ((size_t)pp * MP + row) * DM + l * 8;
        bf16x8 pv = *(const bf16x8*)prp;
        #pragma unroll
        for (int i = 0; i < 8; ++i) v[i] += bf2f((unsigned short)pv[i]);
    }
    float s = 0.f;
    #pragma unroll
    for (int i = 0; i < 8; ++i) s += v[i];
    #pragma unroll
    for (int off = 1; off < 64; off <<= 1) s += __shfl_xor(s, off);
    float mean = s * (1.f / DM);
    float sq = 0.f;
    #pragma unroll
    for (int i = 0; i < 8; ++i) { v[i] -= mean; sq += v[i] * v[i]; }
    #pragma unroll
    for (int off = 1; off < 64; off <<= 1) sq += __shfl_xor(sq, off);
    float inv = rsqrtf(sq * (1.f / DM) + 1e-5f);
    float4 g0 = *(const float4*)(g + l * 8);
    float4 g1 = *(const float4*)(g + l * 8 + 4);
    float4 e0 = *(const float4*)(be + l * 8);
    float4 e1 = *(const float4*)(be + l * 8 + 4);
    float o[8];
    o[0] = v[0]*inv*g0.x + e0.x; o[1] = v[1]*inv*g0.y + e0.y;
    o[2] = v[2]*inv*g0.z + e0.z; o[3] = v[3]*inv*g0.w + e0.w;
    o[4] = v[4]*inv*g1.x + e1.x; o[5] = v[5]*inv*g1.y + e1.y;
    o[6] = v[6]*inv*g1.z + e1.z; o[7] = v[7]*inv*g1.w + e1.w;
    *(float4*)(hp)     = make_float4(o[0], o[1], o[2], o[3]);
    *(float4*)(hp + 4) = make_float4(o[4], o[5], o[6], o[7]);
    ushort4 p0 = {f2bf(o[0]), f2bf(o[1]), f2bf(o[2]), f2bf(o[3])};
    ushort4 p1 = {f2bf(o[4]), f2bf(o[5]), f2bf(o[6]), f2bf(o[7])};
    *(ushort4*)(hbp)     = p0;
    *(ushort4*)(hbp + 4) = p1;
}

// ---------------------------------------------------------------------------
// Fused decoder: one block per batch. cls @ Wd1 + bd1, then @ Wd2 + bd2.
// ---------------------------------------------------------------------------
__global__ __launch_bounds__(256) void dec_kernel(
    const float* __restrict__ h, const float* __restrict__ Wd1,
    const float* __restrict__ bd1, const float* __restrict__ Wd2,
    const float* __restrict__ bd2, float* __restrict__ out)
{
    int b = blockIdx.x;
    int tid = threadIdx.x;
    __shared__ float cs[DM];
    __shared__ float t1s[MLPDIM];
    const float* cls = h + (size_t)b * T * DM;
    cs[tid]       = cls[tid];
    cs[tid + 256] = cls[tid + 256];
    __syncthreads();
    float acc = bd1[tid];
    for (int kx = 0; kx < DM; ++kx)
        acc += cs[kx] * Wd1[(size_t)kx * MLPDIM + tid];
    t1s[tid] = acc;
    __syncthreads();
    if (tid < NCLS) {
        float a2 = bd2[tid];
        for (int kx = 0; kx < MLPDIM; ++kx) a2 += t1s[kx] * Wd2[kx * NCLS + tid];
        out[b * NCLS + tid] = a2;
    }
}

// ---------------------------------------------------------------------------
// Launch
// ---------------------------------------------------------------------------
extern "C" void kernel_launch(void* const* d_in, const int* in_sizes, int n_in,
                              void* d_out, int out_size, void* d_ws, size_t ws_size,
                              hipStream_t stream)
{
    const float* x       = (const float*)d_in[0];
    const int*   adj     = (const int*)  d_in[1];
    const float* W_enc   = (const float*)d_in[2];
    const float* b_enc   = (const float*)d_in[3];
    const float* cls_tok = (const float*)d_in[4];
    const float* pos_emb = (const float*)d_in[5];
    const float* Wq = (const float*)d_in[6];
    const float* bq = (const float*)d_in[7];
    const float* Wk = (const float*)d_in[8];
    const float* bk = (const float*)d_in[9];
    const float* Wv = (const float*)d_in[10];
    const float* bv = (const float*)d_in[11];
    const float* Wo = (const float*)d_in[12];
    const float* bo = (const float*)d_in[13];
    const float* W1 = (const float*)d_in[14];
    const float* b1 = (const float*)d_in[15];
    const float* W2 = (const float*)d_in[16];
    const float* b2 = (const float*)d_in[17];
    const float* g1 = (const float*)d_in[18];
    const float* be1= (const float*)d_in[19];
    const float* g2 = (const float*)d_in[20];
    const float* be2= (const float*)d_in[21];
    const float* Wd1= (const float*)d_in[22];
    const float* bd1= (const float*)d_in[23];
    const float* Wd2= (const float*)d_in[24];
    const float* bd2= (const float*)d_in[25];
    const float* Wg = (const float*)d_in[26];
    const float* ag = (const float*)d_in[27];
    const float* Wgo= (const float*)d_in[28];
    const float* ago= (const float*)d_in[29];
    float* out = (float*)d_out;

    // workspace layout (~91 MB)
    float* ws = (float*)d_ws;
    float* h = ws;
    unsigned short* hb   = (unsigned short*)(h + (size_t)MP * DM);
    unsigned short* qkvb = hb + (size_t)MP * DM;
    unsigned short* ob   = qkvb + (size_t)MP * QKVN;
    unsigned short* f1b  = qkvb;                    // alias qkvb+ob
    unsigned short* Wqkvt= ob + (size_t)MP * DM;
    unsigned short* Wot  = Wqkvt + (size_t)4 * QKVN * DM;
    unsigned short* W1t  = Wot + (size_t)4 * DM * DM;
    unsigned short* W2t  = W1t + (size_t)4 * DM * DFF;
    float* bqkv = (float*)(W2t + (size_t)4 * DFF * DM);
    float* dpart = bqkv + 4 * QKVN;
    unsigned short* vt = (unsigned short*)(dpart + NBATCH * 8 * MLPDIM);  // [40][64][TPAD]
    unsigned short* parts = vt + (size_t)40 * 64 * TPAD;   // [4][MP][512] bf16

    // fused setup | GAT | encoder (mutually independent)
    prelude_kernel<<<PRE_TOTAL, 256, 0, stream>>>(
        x, adj, Wg, ag, Wgo, ago, out + NBATCH * NCLS,
        Wq, Wk, Wv, Wo, W1, W2, bq, bk, bv, Wqkvt, Wot, W1t, W2t, bqkv,
        W_enc, b_enc, cls_tok, pos_emb, h, hb);

    dim3 gqkv (QKVN / 128, MP / 128);        // (12, 41)
    dim3 g2048(DFF / 128, MP / 128);         // (16, 41)
    dim3 gWo  (DM / 128, MP / 128, 2);       // split-K=2
    dim3 gW2  (DM / 128, MP / 128, 4);       // split-K=4
    dim3 gAttn(17, NBATCH * NHEAD);          // 17 q-tiles x 40 bh
    dim3 gVt  (17, NBATCH * NHEAD);          // 17 key-tiles x 40 bh (t<1088)
    int gLN = (ROWS + 3) / 4;

    for (int i = 0; i < 4; ++i) {
        gemm_mfma<<<gqkv, 256, 0, stream>>>(hb, Wqkvt + (size_t)i*QKVN*DM, bqkv + i*QKVN, nullptr, qkvb, QKVN, DM, 0);
        vtrans_kernel<<<gVt, 256, 0, stream>>>(qkvb + 1024, vt, QKVN);
        attn_mfma<<<gAttn, 256, 0, stream>>>(qkvb, qkvb + 512, vt, ob, QKVN);
        gemm_mfma_sk<<<gWo, 256, 0, stream>>>(ob, Wot + (size_t)i*DM*DM, parts, DM, DM);
        add_lnp_kernel<<<gLN, 256, 0, stream>>>(h, parts, 2, bo + i*DM, g1 + i*DM, be1 + i*DM, hb);
        gemm_mfma<<<g2048, 256, 0, stream>>>(hb,  W1t + (size_t)i*DM*DFF, b1 + i*DFF, nullptr, f1b, DFF, DM, 1);
        gemm_mfma_sk<<<gW2, 256, 0, stream>>>(f1b, W2t + (size_t)i*DM*DFF, parts, DM, DFF);
        add_lnp_kernel<<<gLN, 256, 0, stream>>>(h, parts, 4, b2 + i*DM, g2 + i*DM, be2 + i*DM, hb);
    }

    dec_kernel<<<NBATCH, 256, 0, stream>>>(h, Wd1, bd1, Wd2, bd2, out);
}

// Round 9
// 784.268 us; speedup vs baseline: 1.1530x; 1.0871x over previous
//
#include <hip/hip_runtime.h>
#include <hip/hip_bf16.h>
#include <math.h>

// ---------------------------------------------------------------------------
// Model constants
// ---------------------------------------------------------------------------
#define NBATCH 5
#define SEQ    1024
#define T      1025          // SEQ + 1 (cls token)
#define ROWS   (NBATCH * T)  // 5125
#define MP     5248          // ROWS padded to 41*128 for MFMA tiles
#define DM     512
#define DFF    2048
#define NHEAD  8
#define HD     64
#define NTOK   51
#define MLPDIM 256
#define NCLS   7
#define GH     3
#define GHID   64
#define GCLS   5
#define NGRAPH (SEQ * 5)     // 5120
#define QKVN   1536          // fused QKV output width
#define TPAD   1152          // V^T row stride (only t<1025 ever read)

typedef __attribute__((ext_vector_type(8))) short bf16x8;
typedef __attribute__((ext_vector_type(4))) float f32x4;

#define GM_AS(p)  ((const __attribute__((address_space(1))) void*)(p))
#define LDS_AS(p) ((__attribute__((address_space(3))) void*)(p))

__device__ __forceinline__ unsigned short f2bf(float f) {
    unsigned int u = __float_as_uint(f);
    unsigned int r = (u + 0x7FFFu + ((u >> 16) & 1u)) >> 16;
    return (unsigned short)r;
}
__device__ __forceinline__ float bf2f(unsigned short u) {
    return __uint_as_float((unsigned int)u << 16);
}

// ---------------------------------------------------------------------------
// Mega-setup: all weight transposes (fp32->bf16, [K][N]->[N][K]) + bias concat.
// (Kept separate: fusing with GAT/encoder worst-cased VGPR to 216 and ran
// this copy role at 477 GB/s / 10.7% occupancy — measured round 8.)
// ---------------------------------------------------------------------------
__global__ __launch_bounds__(256) void setup_kernel(
    const float* __restrict__ Wq, const float* __restrict__ Wk,
    const float* __restrict__ Wv, const float* __restrict__ Wo_,
    const float* __restrict__ W1, const float* __restrict__ W2,
    const float* __restrict__ bq, const float* __restrict__ bk,
    const float* __restrict__ bv,
    unsigned short* __restrict__ Wqkvt, unsigned short* __restrict__ Wot,
    unsigned short* __restrict__ W1t, unsigned short* __restrict__ W2t,
    float* __restrict__ bqkv)
{
    int id = blockIdx.x;
    if (id >= 12288) {              // bias concat: 4 blocks, one per layer
        int i = id - 12288;
        #pragma unroll
        for (int rep = 0; rep < 2; ++rep) {
            int t = threadIdx.x + rep * 256;
            bqkv[i * QKVN + t]        = bq[i * DM + t];
            bqkv[i * QKVN + 512 + t]  = bk[i * DM + t];
            bqkv[i * QKVN + 1024 + t] = bv[i * DM + t];
        }
        return;
    }
    const float* W; unsigned short* Wt; int K, N, z, bx, by; long dstride;
    if (id < 4096) {                // Wq/Wk/Wv/Wo: 512x512
        int g = id >> 10, lid = id & 1023;
        K = DM; N = DM;
        z = lid >> 8; int r2 = lid & 255; by = r2 >> 4; bx = r2 & 15;
        if (g < 3) { W = (g == 0) ? Wq : (g == 1) ? Wk : Wv;
                     Wt = Wqkvt + (size_t)g * DM * DM; dstride = (long)QKVN * DM; }
        else       { W = Wo_; Wt = Wot; dstride = (long)DM * DM; }
    } else if (id < 8192) {         // W1: K=512, N=2048
        int lid = id - 4096;
        K = DM; N = DFF;
        z = lid >> 10; int r2 = lid & 1023; by = r2 >> 6; bx = r2 & 63;
        W = W1; Wt = W1t; dstride = (long)DM * DFF;
    } else {                        // W2: K=2048, N=512
        int lid = id - 8192;
        K = DFF; N = DM;
        z = lid >> 10; int r2 = lid & 1023; by = r2 >> 4; bx = r2 & 15;
        W = W2; Wt = W2t; dstride = (long)DFF * DM;
    }
    const float* Wm = W + (size_t)z * K * N;
    unsigned short* Wo2 = Wt + (size_t)z * dstride;
    __shared__ float tile[32][33];
    int bX = bx * 32, bY = by * 32;
    int tx = threadIdx.x & 31, ty = threadIdx.x >> 5;
    #pragma unroll
    for (int i = 0; i < 32; i += 8)
        tile[ty + i][tx] = Wm[(size_t)(bY + ty + i) * N + bX + tx];
    __syncthreads();
    #pragma unroll
    for (int i = 0; i < 32; i += 8)
        Wo2[(size_t)(bX + ty + i) * K + bY + tx] = f2bf(tile[tx][ty + i]);
}

// ---------------------------------------------------------------------------
// bf16 MFMA GEMM: C[M][N] = A[M][K] @ Bt[N][K]^T + bias. 128x128 tile, BK=64.
// Epilogue repacks the C tile through LDS (stride 136 ushorts, 16B-aligned
// rows): 64 scalar 2B global stores/thread -> 8 coalesced 16B stores/thread.
// Values bit-identical (same f2bf(acc+bias)); only the store path changes.
// ---------------------------------------------------------------------------
__global__ __launch_bounds__(256) void gemm_mfma(
    const unsigned short* __restrict__ A, const unsigned short* __restrict__ Bt,
    const float* __restrict__ bias,
    unsigned short* __restrict__ Cb, int N, int K, int relu)
{
    __shared__ unsigned short sm[128 * 136];     // staging (2x 128x64) + C repack
    unsigned short* As = sm;
    unsigned short* Bs = sm + 128 * 64;
    int tid = threadIdx.x;
    int l = tid & 63, w = tid >> 6;
    int wr = w & 1, wc = w >> 1;
    int mlane = l & 15, quad = l >> 4;
    int m0 = blockIdx.y * 128, n0 = blockIdx.x * 128;

    f32x4 acc[4][4] = {};

    for (int k0 = 0; k0 < K; k0 += 64) {
        __syncthreads();
        #pragma unroll
        for (int it = 0; it < 4; ++it) {
            int c = tid + it * 256;
            int row = c >> 3, cc = c & 7;
            const unsigned short* ga = A  + (size_t)(m0 + row) * K + k0 + cc * 8;
            __builtin_amdgcn_global_load_lds(GM_AS(ga), LDS_AS(As + c * 8), 16, 0, 0);
            const unsigned short* gb = Bt + (size_t)(n0 + row) * K + k0 + cc * 8;
            __builtin_amdgcn_global_load_lds(GM_AS(gb), LDS_AS(Bs + c * 8), 16, 0, 0);
        }
        __syncthreads();
        #pragma unroll
        for (int half = 0; half < 2; ++half) {
            int ko = half * 32 + quad * 8;
            bf16x8 afrag[4], bfrag[4];
            #pragma unroll
            for (int mi = 0; mi < 4; ++mi)
                afrag[mi] = *(const bf16x8*)(As + (wr * 64 + mi * 16 + mlane) * 64 + ko);
            #pragma unroll
            for (int ni = 0; ni < 4; ++ni)
                bfrag[ni] = *(const bf16x8*)(Bs + (wc * 64 + ni * 16 + mlane) * 64 + ko);
            #pragma unroll
            for (int mi = 0; mi < 4; ++mi)
                #pragma unroll
                for (int ni = 0; ni < 4; ++ni)
                    acc[mi][ni] = __builtin_amdgcn_mfma_f32_16x16x32_bf16(
                        afrag[mi], bfrag[ni], acc[mi][ni], 0, 0, 0);
        }
    }

    __syncthreads();                 // all waves done reading As/Bs
    #pragma unroll
    for (int mi = 0; mi < 4; ++mi)
        #pragma unroll
        for (int r = 0; r < 4; ++r) {
            int row = wr * 64 + mi * 16 + quad * 4 + r;
            #pragma unroll
            for (int ni = 0; ni < 4; ++ni) {
                int col = wc * 64 + ni * 16 + mlane;
                float val = acc[mi][ni][r] + bias[n0 + col];
                if (relu) val = fmaxf(val, 0.f);
                sm[row * 136 + col] = f2bf(val);
            }
        }
    __syncthreads();
    #pragma unroll
    for (int j = 0; j < 8; ++j) {
        int row = j * 16 + (tid >> 4);
        int col = (tid & 15) * 8;
        bf16x8 vv = *(const bf16x8*)(sm + row * 136 + col);
        *(bf16x8*)(Cb + (size_t)(m0 + row) * N + n0 + col) = vv;
    }
}

// ---------------------------------------------------------------------------
// Split-K bf16 MFMA GEMM: writes bf16 partials (combined in add_lnp), with
// the same LDS-repacked coalesced epilogue.
// (fp32 atomicAdd variant measured 52us/dispatch: atomic-throughput-bound.)
// ---------------------------------------------------------------------------
__global__ __launch_bounds__(256) void gemm_mfma_sk(
    const unsigned short* __restrict__ A, const unsigned short* __restrict__ Bt,
    unsigned short* __restrict__ part, int N, int K)
{
    __shared__ unsigned short sm[128 * 136];
    unsigned short* As = sm;
    unsigned short* Bs = sm + 128 * 64;
    int tid = threadIdx.x;
    int l = tid & 63, w = tid >> 6;
    int wr = w & 1, wc = w >> 1;
    int mlane = l & 15, quad = l >> 4;
    int m0 = blockIdx.y * 128, n0 = blockIdx.x * 128;
    int kper = K / gridDim.z;
    int kbeg = blockIdx.z * kper;

    f32x4 acc[4][4] = {};

    for (int k0 = kbeg; k0 < kbeg + kper; k0 += 64) {
        __syncthreads();
        #pragma unroll
        for (int it = 0; it < 4; ++it) {
            int c = tid + it * 256;
            int row = c >> 3, cc = c & 7;
            const unsigned short* ga = A  + (size_t)(m0 + row) * K + k0 + cc * 8;
            __builtin_amdgcn_global_load_lds(GM_AS(ga), LDS_AS(As + c * 8), 16, 0, 0);
            const unsigned short* gb = Bt + (size_t)(n0 + row) * K + k0 + cc * 8;
            __builtin_amdgcn_global_load_lds(GM_AS(gb), LDS_AS(Bs + c * 8), 16, 0, 0);
        }
        __syncthreads();
        #pragma unroll
        for (int half = 0; half < 2; ++half) {
            int ko = half * 32 + quad * 8;
            bf16x8 afrag[4], bfrag[4];
            #pragma unroll
            for (int mi = 0; mi < 4; ++mi)
                afrag[mi] = *(const bf16x8*)(As + (wr * 64 + mi * 16 + mlane) * 64 + ko);
            #pragma unroll
            for (int ni = 0; ni < 4; ++ni)
                bfrag[ni] = *(const bf16x8*)(Bs + (wc * 64 + ni * 16 + mlane) * 64 + ko);
            #pragma unroll
            for (int mi = 0; mi < 4; ++mi)
                #pragma unroll
                for (int ni = 0; ni < 4; ++ni)
                    acc[mi][ni] = __builtin_amdgcn_mfma_f32_16x16x32_bf16(
                        afrag[mi], bfrag[ni], acc[mi][ni], 0, 0, 0);
        }
    }

    __syncthreads();
    #pragma unroll
    for (int mi = 0; mi < 4; ++mi)
        #pragma unroll
        for (int r = 0; r < 4; ++r) {
            int row = wr * 64 + mi * 16 + quad * 4 + r;
            #pragma unroll
            for (int ni = 0; ni < 4; ++ni) {
                int col = wc * 64 + ni * 16 + mlane;
                sm[row * 136 + col] = f2bf(acc[mi][ni][r]);
            }
        }
    __syncthreads();
    unsigned short* pz = part + (size_t)blockIdx.z * MP * N;
    #pragma unroll
    for (int j = 0; j < 8; ++j) {
        int row = j * 16 + (tid >> 4);
        int col = (tid & 15) * 8;
        bf16x8 vv = *(const bf16x8*)(sm + row * 136 + col);
        *(bf16x8*)(pz + (size_t)(m0 + row) * N + n0 + col) = vv;
    }
}

// ---------------------------------------------------------------------------
// V transpose per layer: vb rows (b,t) stride qs -> vt[(bh*64+d)][TPAD].
// x-grid = 17 tiles (covers t < 1088; only t < 1025 is ever read).
// ---------------------------------------------------------------------------
__global__ __launch_bounds__(256) void vtrans_kernel(
    const unsigned short* __restrict__ vb, unsigned short* __restrict__ vt, int qs)
{
    __shared__ unsigned short tile[64][72];
    int bh = blockIdx.y;
    int b = bh >> 3, h = bh & 7;
    int t0 = blockIdx.x * 64;
    int tid = threadIdx.x;
    #pragma unroll
    for (int it = 0; it < 2; ++it) {
        int c = tid + it * 256;
        int key = c >> 3, cc = c & 7;
        int gk = t0 + key; if (gk >= T) gk = T - 1;
        *(bf16x8*)(&tile[key][cc * 8]) =
            *(const bf16x8*)(vb + ((size_t)b * T + gk) * qs + h * HD + cc * 8);
    }
    __syncthreads();
    #pragma unroll
    for (int it = 0; it < 2; ++it) {
        int c = tid + it * 256;
        int d = c >> 3, cc = c & 7;
        unsigned short tmp[8];
        #pragma unroll
        for (int j = 0; j < 8; ++j) tmp[j] = tile[cc * 8 + j][d];
        *(bf16x8*)(vt + ((size_t)bh * 64 + d) * TPAD + t0 + cc * 8) = *(bf16x8*)tmp;
    }
}

// ---------------------------------------------------------------------------
// bf16 MFMA flash attention. NR=8 rounds of 128 keys cover t in [0,1024);
// the single remaining key t=1024 is a scalar rank-1 tail.
// Block = 64 queries x (b,h); 4 waves x 16 q — measured local optimum
// (2-wave: 52us occupancy-bound; 8-wave/128q: +12us; setprio: +9us).
// ---------------------------------------------------------------------------
#define AQT 64
#define NR 8    // rounds of 128 keys over [0,1024)
__global__ __launch_bounds__(256) void attn_mfma(
    const unsigned short* __restrict__ qb, const unsigned short* __restrict__ kb,
    const unsigned short* __restrict__ vt, unsigned short* __restrict__ ob,
    int qs)
{
    __shared__ unsigned short Ks[128 * 72];    // [key][72]
    __shared__ unsigned short Vs[64 * 136];    // [d][136] keys contiguous
    __shared__ unsigned short Ps[4][16 * 72];
    int bh = blockIdx.y;
    int b = bh >> 3, h = bh & 7;
    int t0 = blockIdx.x * AQT;
    int tid = threadIdx.x;
    int l = tid & 63, w = tid >> 6;
    int ml = l & 15, quad = l >> 4;
    size_t rowbase = (size_t)b * T;
    const unsigned short* vtb = vt + (size_t)bh * 64 * TPAD;

    int qrow = t0 + w * 16 + ml; if (qrow >= T) qrow = T - 1;
    const unsigned short* qp = qb + (rowbase + qrow) * qs + h * HD + quad * 8;
    bf16x8 qf0 = *(const bf16x8*)qp;
    bf16x8 qf1 = *(const bf16x8*)(qp + 32);

    int krow = tid >> 3, kcc = tid & 7;
    int vd   = tid >> 4, vck = tid & 15;

    f32x4 oacc[4] = {};
    float lrow[4] = {0.f, 0.f, 0.f, 0.f};

    bf16x8 kr[4], vr[4];
    #pragma unroll
    for (int i = 0; i < 4; ++i) {
        int gk = krow + i * 32;
        kr[i] = *(const bf16x8*)(kb + (rowbase + gk) * qs + h * HD + kcc * 8);
        vr[i] = *(const bf16x8*)(vtb + (size_t)(vd + i * 16) * TPAD + vck * 8);
    }

    for (int rnd = 0; rnd < NR; ++rnd) {
        __syncthreads();
        #pragma unroll
        for (int i = 0; i < 4; ++i) {
            *(bf16x8*)(Ks + (krow + i * 32) * 72 + kcc * 8) = kr[i];
            *(bf16x8*)(Vs + (vd + i * 16) * 136 + vck * 8) = vr[i];
        }
        __syncthreads();
        if (rnd + 1 < NR) {
            int n0k = (rnd + 1) * 128;
            #pragma unroll
            for (int i = 0; i < 4; ++i) {
                int gk = n0k + krow + i * 32;
                kr[i] = *(const bf16x8*)(kb + (rowbase + gk) * qs + h * HD + kcc * 8);
                vr[i] = *(const bf16x8*)(vtb + (size_t)(vd + i * 16) * TPAD + n0k + vck * 8);
            }
        }

        #pragma unroll
        for (int p = 0; p < 2; ++p) {
            int kb0 = p * 64;
            f32x4 s[4] = {};
            #pragma unroll
            for (int ni = 0; ni < 4; ++ni) {
                const unsigned short* kfp = Ks + (kb0 + ni * 16 + ml) * 72 + quad * 8;
                bf16x8 kf0 = *(const bf16x8*)kfp;
                bf16x8 kf1 = *(const bf16x8*)(kfp + 32);
                s[ni] = __builtin_amdgcn_mfma_f32_16x16x32_bf16(qf0, kf0, s[ni], 0, 0, 0);
                s[ni] = __builtin_amdgcn_mfma_f32_16x16x32_bf16(qf1, kf1, s[ni], 0, 0, 0);
            }
            // all staged keys are < 1024 < T: no validity predicate needed
            #pragma unroll
            for (int ni = 0; ni < 4; ++ni) {
                #pragma unroll
                for (int r = 0; r < 4; ++r) {
                    float pv = __expf(s[ni][r] * 0.125f);
                    s[ni][r] = pv;
                    lrow[r] += pv;
                }
            }
            unsigned short* pw = Ps[w];
            #pragma unroll
            for (int r = 0; r < 4; ++r)
                #pragma unroll
                for (int ni = 0; ni < 4; ++ni)
                    pw[(quad * 4 + r) * 72 + ((ni * 16 + ml) ^ (quad << 4))] = f2bf(s[ni][r]);
            int sw = ((ml >> 2) & 3) << 4;
            #pragma unroll
            for (int kc = 0; kc < 2; ++kc) {
                bf16x8 pf = *(const bf16x8*)(pw + ml * 72 + ((kc * 32 + quad * 8) ^ sw));
                #pragma unroll
                for (int ni = 0; ni < 4; ++ni) {
                    bf16x8 vf = *(const bf16x8*)(Vs + (ni * 16 + ml) * 136 + kb0 + kc * 32 + quad * 8);
                    oacc[ni] = __builtin_amdgcn_mfma_f32_16x16x32_bf16(pf, vf, oacc[ni], 0, 0, 0);
                }
            }
        }
    }

    #pragma unroll
    for (int r = 0; r < 4; ++r) {
        #pragma unroll
        for (int off = 1; off < 16; off <<= 1)
            lrow[r] += __shfl_xor(lrow[r], off);
    }

    // ---- tail: key t = 1024 (rank-1 update, no MFMA round) ----
    {
        const unsigned short* kp = kb + (rowbase + SEQ) * qs + h * HD + quad * 8;
        bf16x8 kf0 = *(const bf16x8*)kp;
        bf16x8 kf1 = *(const bf16x8*)(kp + 32);
        float dot = 0.f;
        #pragma unroll
        for (int j = 0; j < 8; ++j) {
            dot += bf2f((unsigned short)qf0[j]) * bf2f((unsigned short)kf0[j]);
            dot += bf2f((unsigned short)qf1[j]) * bf2f((unsigned short)kf1[j]);
        }
        dot += __shfl_xor(dot, 16);
        dot += __shfl_xor(dot, 32);          // every lane now holds the full dot for q-row ml
        float pe = __expf(dot * 0.125f);
        float vv[4];
        #pragma unroll
        for (int ni = 0; ni < 4; ++ni)
            vv[ni] = bf2f(vtb[(size_t)(ni * 16 + ml) * TPAD + SEQ]);
        #pragma unroll
        for (int r = 0; r < 4; ++r) {
            float pr = __shfl(pe, quad * 4 + r);
            lrow[r] += pr;
            #pragma unroll
            for (int ni = 0; ni < 4; ++ni)
                oacc[ni][r] += pr * vv[ni];
        }
    }

    #pragma unroll
    for (int r = 0; r < 4; ++r) {
        int grow = t0 + w * 16 + quad * 4 + r;
        if (grow >= T) continue;
        float inv = 1.f / lrow[r];
        unsigned short* op = ob + (rowbase + grow) * DM + h * HD;
        #pragma unroll
        for (int ni = 0; ni < 4; ++ni)
            op[ni * 16 + ml] = f2bf(oacc[ni][r] * inv);
    }
}

// ---------------------------------------------------------------------------
// Encoder: 8 rows per block, W_enc held in registers per k-step and reused
// across rows (L2 traffic 533 MB -> 67 MB). Writes fp32 h and bf16 shadow hb.
// ---------------------------------------------------------------------------
#define ENC_RPB 8
__global__ __launch_bounds__(256) void encoder_kernel(
    const float* __restrict__ x, const float* __restrict__ W_enc,
    const float* __restrict__ b_enc, const float* __restrict__ cls_tok,
    const float* __restrict__ pos_emb, float* __restrict__ h,
    unsigned short* __restrict__ hb)
{
    int r0 = blockIdx.x * ENC_RPB;
    int tid = threadIdx.x;
    __shared__ float xs[ENC_RPB][NTOK + 1];
    for (int i = tid; i < ENC_RPB * NTOK; i += 256) {
        int rr = i / NTOK, c = i % NTOK;
        int row = r0 + rr;
        float v = 0.f;
        if (row < ROWS) {
            int b = row / T, tt = row % T;
            if (tt > 0)
                v = x[((size_t)b * SEQ + (tt - 1)) * NTOK + c];
        }
        xs[rr][c] = v;
    }
    __syncthreads();
    #pragma unroll
    for (int rep = 0; rep < 2; ++rep) {
        int d = tid + rep * 256;
        float acc[ENC_RPB];
        #pragma unroll
        for (int rr = 0; rr < ENC_RPB; ++rr) acc[rr] = 0.f;
        for (int kx = 0; kx < NTOK; ++kx) {
            float wv = W_enc[kx * DM + d];
            #pragma unroll
            for (int rr = 0; rr < ENC_RPB; ++rr)
                acc[rr] += xs[rr][kx] * wv;
        }
        float be = b_enc[d];
        float ct = cls_tok[d];
        #pragma unroll
        for (int rr = 0; rr < ENC_RPB; ++rr) {
            int row = r0 + rr;
            if (row < ROWS) {
                int b = row / T, tt = row % T;
                float res;
                if (tt == 0) res = ct + pos_emb[d];
                else         res = acc[rr] + be + pos_emb[(size_t)tt * DM + d];
                h[(size_t)row * DM + d]  = res;
                hb[(size_t)row * DM + d] = f2bf(res);
            }
        }
    }
}

// ---------------------------------------------------------------------------
// Fused (sum of np bf16 partials + bias) residual + LayerNorm, wave-per-row
// ---------------------------------------------------------------------------
__global__ __launch_bounds__(256) void add_lnp_kernel(
    float* __restrict__ h, const unsigned short* __restrict__ part, int np,
    const float* __restrict__ bias, const float* __restrict__ g,
    const float* __restrict__ be, unsigned short* __restrict__ hb)
{
    int w = threadIdx.x >> 6, l = threadIdx.x & 63;
    int row = blockIdx.x * 4 + w;
    if (row >= ROWS) return;
    float* hp = h + (size_t)row * DM + l * 8;
    unsigned short* hbp = hb + (size_t)row * DM + l * 8;
    float4 a0 = *(const float4*)(hp);
    float4 a1 = *(const float4*)(hp + 4);
    float4 b0 = *(const float4*)(bias + l * 8);
    float4 b1 = *(const float4*)(bias + l * 8 + 4);
    float v[8] = {a0.x + b0.x, a0.y + b0.y, a0.z + b0.z, a0.w + b0.w,
                  a1.x + b1.x, a1.y + b1.y, a1.z + b1.z, a1.w + b1.w};
    for (int pp = 0; pp < np; ++pp) {
        const unsigned short* prp = part + ((size_t)pp * MP + row) * DM + l * 8;
        bf16x8 pv = *(const bf16x8*)prp;
        #pragma unroll
        for (int i = 0; i < 8; ++i) v[i] += bf2f((unsigned short)pv[i]);
    }
    float s = 0.f;
    #pragma unroll
    for (int i = 0; i < 8; ++i) s += v[i];
    #pragma unroll
    for (int off = 1; off < 64; off <<= 1) s += __shfl_xor(s, off);
    float mean = s * (1.f / DM);
    float sq = 0.f;
    #pragma unroll
    for (int i = 0; i < 8; ++i) { v[i] -= mean; sq += v[i] * v[i]; }
    #pragma unroll
    for (int off = 1; off < 64; off <<= 1) sq += __shfl_xor(sq, off);
    float inv = rsqrtf(sq * (1.f / DM) + 1e-5f);
    float4 g0 = *(const float4*)(g + l * 8);
    float4 g1 = *(const float4*)(g + l * 8 + 4);
    float4 e0 = *(const float4*)(be + l * 8);
    float4 e1 = *(const float4*)(be + l * 8 + 4);
    float o[8];
    o[0] = v[0]*inv*g0.x + e0.x; o[1] = v[1]*inv*g0.y + e0.y;
    o[2] = v[2]*inv*g0.z + e0.z; o[3] = v[3]*inv*g0.w + e0.w;
    o[4] = v[4]*inv*g1.x + e1.x; o[5] = v[5]*inv*g1.y + e1.y;
    o[6] = v[6]*inv*g1.z + e1.z; o[7] = v[7]*inv*g1.w + e1.w;
    *(float4*)(hp)     = make_float4(o[0], o[1], o[2], o[3]);
    *(float4*)(hp + 4) = make_float4(o[4], o[5], o[6], o[7]);
    ushort4 p0 = {f2bf(o[0]), f2bf(o[1]), f2bf(o[2]), f2bf(o[3])};
    ushort4 p1 = {f2bf(o[4]), f2bf(o[5]), f2bf(o[6]), f2bf(o[7])};
    *(ushort4*)(hbp)     = p0;
    *(ushort4*)(hbp + 4) = p1;
}

// ---------------------------------------------------------------------------
// Fused decoder: one block per batch. cls @ Wd1 + bd1, then @ Wd2 + bd2.
// ---------------------------------------------------------------------------
__global__ __launch_bounds__(256) void dec_kernel(
    const float* __restrict__ h, const float* __restrict__ Wd1,
    const float* __restrict__ bd1, const float* __restrict__ Wd2,
    const float* __restrict__ bd2, float* __restrict__ out)
{
    int b = blockIdx.x;
    int tid = threadIdx.x;
    __shared__ float cs[DM];
    __shared__ float t1s[MLPDIM];
    const float* cls = h + (size_t)b * T * DM;
    cs[tid]       = cls[tid];
    cs[tid + 256] = cls[tid + 256];
    __syncthreads();
    float acc = bd1[tid];
    for (int kx = 0; kx < DM; ++kx)
        acc += cs[kx] * Wd1[(size_t)kx * MLPDIM + tid];
    t1s[tid] = acc;
    __syncthreads();
    if (tid < NCLS) {
        float a2 = bd2[tid];
        for (int kx = 0; kx < MLPDIM; ++kx) a2 += t1s[kx] * Wd2[kx * NCLS + tid];
        out[b * NCLS + tid] = a2;
    }
}

// ---------------------------------------------------------------------------
// GAT: one 64-thread block per graph. Inner dims of hb/o1 padded 64->65 so
// reduction lanes (distinct n at fixed f) land on distinct banks (65 % 32 = 1).
// ---------------------------------------------------------------------------
__global__ __launch_bounds__(64) void gat_kernel(
    const float* __restrict__ x, const int* __restrict__ adj,
    const float* __restrict__ Wg, const float* __restrict__ ag,
    const float* __restrict__ Wgo, const float* __restrict__ ago,
    float* __restrict__ out)
{
    int g = blockIdx.x;
    int s = g / 5, jj = g % 5;
    int tid = threadIdx.x;
    __shared__ float xs[5][3];
    __shared__ int adjs[25];
    __shared__ float hb[GH][5][GHID + 1];
    __shared__ float o1[GH][5][GHID + 1];
    __shared__ float srcb[GH][5], dstb[GH][5];
    __shared__ float attb[GH][5][5];
    __shared__ float h2[5][5], src2[5], dst2[5], att2[5][5], o2[5][5];

    if (tid < 15) { int n = tid / 3, c = tid % 3;
        xs[n][c] = x[(size_t)n * SEQ * NTOK + (size_t)s * NTOK + jj * 3 + c]; }
    if (tid < 25) adjs[tid] = adj[tid];
    __syncthreads();

    #pragma unroll
    for (int hh = 0; hh < GH; ++hh)
        #pragma unroll
        for (int n = 0; n < 5; ++n)
            hb[hh][n][tid] = xs[n][0] * Wg[hh * 192 + tid]
                           + xs[n][1] * Wg[hh * 192 + 64 + tid]
                           + xs[n][2] * Wg[hh * 192 + 128 + tid];
    __syncthreads();

    if (tid < 15) { int hh = tid / 5, n = tid % 5; float a = 0.f;
        for (int f = 0; f < GHID; ++f) a += hb[hh][n][f] * ag[hh * 128 + f];
        srcb[hh][n] = a;
    } else if (tid >= 32 && tid < 47) { int t2 = tid - 32; int hh = t2 / 5, n = t2 % 5; float a = 0.f;
        for (int f = 0; f < GHID; ++f) a += hb[hh][n][f] * ag[hh * 128 + 64 + f];
        dstb[hh][n] = a;
    }
    __syncthreads();

    if (tid < 15) { int hh = tid / 5, i = tid % 5;
        float e[5]; float mx = -1e30f;
        #pragma unroll
        for (int j2 = 0; j2 < 5; ++j2) {
            float ev = srcb[hh][i] + dstb[hh][j2];
            ev = ev > 0.f ? ev : 0.2f * ev;
            e[j2] = ev;
            if (adjs[i * 5 + j2] && ev > mx) mx = ev;
        }
        float sum = 0.f;
        #pragma unroll
        for (int j2 = 0; j2 < 5; ++j2) {
            float p = adjs[i * 5 + j2] ? expf(e[j2] - mx) : 0.f;
            e[j2] = p; sum += p;
        }
        float inv = 1.f / sum;
        #pragma unroll
        for (int j2 = 0; j2 < 5; ++j2) attb[hh][i][j2] = e[j2] * inv;
    }
    __syncthreads();

    #pragma unroll
    for (int hh = 0; hh < GH; ++hh)
        #pragma unroll
        for (int n = 0; n < 5; ++n) {
            float a = 0.f;
            #pragma unroll
            for (int j2 = 0; j2 < 5; ++j2) a += attb[hh][n][j2] * hb[hh][j2][tid];
            o1[hh][n][tid] = a > 0.f ? a : expm1f(a);
        }
    __syncthreads();

    if (tid < 25) { int n = tid / 5, m = tid % 5; float a = 0.f;
        for (int hh = 0; hh < GH; ++hh)
            for (int f = 0; f < GHID; ++f)
                a += o1[hh][n][f] * Wgo[(hh * GHID + f) * GCLS + m];
        h2[n][m] = a;
    }
    __syncthreads();

    if (tid < 5) { float a = 0.f;
        for (int m = 0; m < GCLS; ++m) a += h2[tid][m] * ago[m];
        src2[tid] = a;
    } else if (tid >= 8 && tid < 13) { int n = tid - 8; float a = 0.f;
        for (int m = 0; m < GCLS; ++m) a += h2[n][m] * ago[GCLS + m];
        dst2[n] = a;
    }
    __syncthreads();

    if (tid < 5) { int i = tid;
        float e[5]; float mx = -1e30f;
        #pragma unroll
        for (int j2 = 0; j2 < 5; ++j2) {
            float ev = src2[i] + dst2[j2];
            ev = ev > 0.f ? ev : 0.2f * ev;
            e[j2] = ev;
            if (adjs[i * 5 + j2] && ev > mx) mx = ev;
        }
        float sum = 0.f;
        #pragma unroll
        for (int j2 = 0; j2 < 5; ++j2) {
            float p = adjs[i * 5 + j2] ? expf(e[j2] - mx) : 0.f;
            e[j2] = p; sum += p;
        }
        float inv = 1.f / sum;
        #pragma unroll
        for (int j2 = 0; j2 < 5; ++j2) att2[i][j2] = e[j2] * inv;
    }
    __syncthreads();

    if (tid < 25) { int n = tid / 5, m = tid % 5; float a = 0.f;
        #pragma unroll
        for (int j2 = 0; j2 < 5; ++j2) a += att2[n][j2] * h2[j2][m];
        o2[n][m] = a > 0.f ? a : expm1f(a);
    }
    __syncthreads();

    if (tid < 5) { int n = tid;
        float mx = o2[n][0];
        #pragma unroll
        for (int m = 1; m < GCLS; ++m) mx = fmaxf(mx, o2[n][m]);
        float sum = 0.f;
        #pragma unroll
        for (int m = 0; m < GCLS; ++m) sum += expf(o2[n][m] - mx);
        float ls = logf(sum);
        #pragma unroll
        for (int m = 0; m < GCLS; ++m)
            out[(size_t)g * 25 + n * 5 + m] = o2[n][m] - mx - ls;
    }
}

// ---------------------------------------------------------------------------
// Launch
// ---------------------------------------------------------------------------
extern "C" void kernel_launch(void* const* d_in, const int* in_sizes, int n_in,
                              void* d_out, int out_size, void* d_ws, size_t ws_size,
                              hipStream_t stream)
{
    const float* x       = (const float*)d_in[0];
    const int*   adj     = (const int*)  d_in[1];
    const float* W_enc   = (const float*)d_in[2];
    const float* b_enc   = (const float*)d_in[3];
    const float* cls_tok = (const float*)d_in[4];
    const float* pos_emb = (const float*)d_in[5];
    const float* Wq = (const float*)d_in[6];
    const float* bq = (const float*)d_in[7];
    const float* Wk = (const float*)d_in[8];
    const float* bk = (const float*)d_in[9];
    const float* Wv = (const float*)d_in[10];
    const float* bv = (const float*)d_in[11];
    const float* Wo = (const float*)d_in[12];
    const float* bo = (const float*)d_in[13];
    const float* W1 = (const float*)d_in[14];
    const float* b1 = (const float*)d_in[15];
    const float* W2 = (const float*)d_in[16];
    const float* b2 = (const float*)d_in[17];
    const float* g1 = (const float*)d_in[18];
    const float* be1= (const float*)d_in[19];
    const float* g2 = (const float*)d_in[20];
    const float* be2= (const float*)d_in[21];
    const float* Wd1= (const float*)d_in[22];
    const float* bd1= (const float*)d_in[23];
    const float* Wd2= (const float*)d_in[24];
    const float* bd2= (const float*)d_in[25];
    const float* Wg = (const float*)d_in[26];
    const float* ag = (const float*)d_in[27];
    const float* Wgo= (const float*)d_in[28];
    const float* ago= (const float*)d_in[29];
    float* out = (float*)d_out;

    // workspace layout (~91 MB)
    float* ws = (float*)d_ws;
    float* h = ws;
    unsigned short* hb   = (unsigned short*)(h + (size_t)MP * DM);
    unsigned short* qkvb = hb + (size_t)MP * DM;
    unsigned short* ob   = qkvb + (size_t)MP * QKVN;
    unsigned short* f1b  = qkvb;                    // alias qkvb+ob
    unsigned short* Wqkvt= ob + (size_t)MP * DM;
    unsigned short* Wot  = Wqkvt + (size_t)4 * QKVN * DM;
    unsigned short* W1t  = Wot + (size_t)4 * DM * DM;
    unsigned short* W2t  = W1t + (size_t)4 * DM * DFF;
    float* bqkv = (float*)(W2t + (size_t)4 * DFF * DM);
    float* dpart = bqkv + 4 * QKVN;
    unsigned short* vt = (unsigned short*)(dpart + NBATCH * 8 * MLPDIM);  // [40][64][TPAD]
    unsigned short* parts = vt + (size_t)40 * 64 * TPAD;   // [4][MP][512] bf16

    setup_kernel<<<12292, 256, 0, stream>>>(Wq, Wk, Wv, Wo, W1, W2, bq, bk, bv,
                                            Wqkvt, Wot, W1t, W2t, bqkv);

    gat_kernel<<<NGRAPH, 64, 0, stream>>>(x, adj, Wg, ag, Wgo, ago, out + NBATCH * NCLS);
    encoder_kernel<<<(ROWS + ENC_RPB - 1) / ENC_RPB, 256, 0, stream>>>(
        x, W_enc, b_enc, cls_tok, pos_emb, h, hb);

    dim3 gqkv (QKVN / 128, MP / 128);        // (12, 41)
    dim3 g2048(DFF / 128, MP / 128);         // (16, 41)
    dim3 gWo  (DM / 128, MP / 128, 2);       // split-K=2
    dim3 gW2  (DM / 128, MP / 128, 4);       // split-K=4
    dim3 gAttn(17, NBATCH * NHEAD);          // 17 q-tiles x 40 bh
    dim3 gVt  (17, NBATCH * NHEAD);          // 17 key-tiles x 40 bh (t<1088)
    int gLN = (ROWS + 3) / 4;

    for (int i = 0; i < 4; ++i) {
        gemm_mfma<<<gqkv, 256, 0, stream>>>(hb, Wqkvt + (size_t)i*QKVN*DM, bqkv + i*QKVN, qkvb, QKVN, DM, 0);
        vtrans_kernel<<<gVt, 256, 0, stream>>>(qkvb + 1024, vt, QKVN);
        attn_mfma<<<gAttn, 256, 0, stream>>>(qkvb, qkvb + 512, vt, ob, QKVN);
        gemm_mfma_sk<<<gWo, 256, 0, stream>>>(ob, Wot + (size_t)i*DM*DM, parts, DM, DM);
        add_lnp_kernel<<<gLN, 256, 0, stream>>>(h, parts, 2, bo + i*DM, g1 + i*DM, be1 + i*DM, hb);
        gemm_mfma<<<g2048, 256, 0, stream>>>(hb,  W1t + (size_t)i*DM*DFF, b1 + i*DFF, f1b, DFF, DM, 1);
        gemm_mfma_sk<<<gW2, 256, 0, stream>>>(f1b, W2t + (size_t)i*DM*DFF, parts, DM, DFF);
        add_lnp_kernel<<<gLN, 256, 0, stream>>>(h, parts, 4, b2 + i*DM, g2 + i*DM, be2 + i*DM, hb);
    }

    dec_kernel<<<NBATCH, 256, 0, stream>>>(h, Wd1, bd1, Wd2, bd2, out);
}